// Round 1
// baseline (1220.762 us; speedup 1.0000x reference)
//
#include <hip/hip_runtime.h>
#include <hip/hip_bf16.h>
#include <stdint.h>

#define NN 50000
#define NE 800000
#define HH 128

typedef __bf16 bf16x8 __attribute__((ext_vector_type(8)));
typedef float  f32x4  __attribute__((ext_vector_type(4)));

__device__ __forceinline__ unsigned short f2bf(float f) {
  union { float f; uint32_t u; } v; v.f = f;
  uint32_t r = v.u + 0x7FFFu + ((v.u >> 16) & 1u);
  return (unsigned short)(r >> 16);
}
__device__ __forceinline__ float silu_f(float x) { return x / (1.f + __expf(-x)); }
__device__ __forceinline__ float sigm_f(float x) { return 1.f / (1.f + __expf(-x)); }

typedef const __attribute__((address_space(1))) void gvoid_t;
typedef __attribute__((address_space(3))) void lvoid_t;
// async global->LDS, 16B per lane; dst must be wave-uniform (HW adds lane*16)
__device__ __forceinline__ void gll16(const void* g, void* l) {
  __builtin_amdgcn_global_load_lds((gvoid_t*)g, (lvoid_t*)l, 16, 0, 0);
}

// All LDS tiles: [128 rows][32 k] bf16 (8KB blocks), 16B chunk c stored at c ^ ((row>>1)&3)
__device__ __forceinline__ bf16x8 frag_ld(const short* blk, int row, int q) {
  int c = q ^ ((row >> 1) & 3);
  return *(const bf16x8*)(blk + row * 32 + c * 8);
}

// ---------------- weight prep: transpose to [kk][n][32k] swizzled bf16 ----------------
__global__ void k_prep_weights(const float* We1, const float* We2, const float* Wn1,
                               const float* Wn2, const float* cW1, const float* cW2,
                               short* W1sw, short* W2sw, short* Wn1sw, short* Wn2sw,
                               short* cW1sw, short* cW2sw) {
  int idx = blockIdx.x * 256 + threadIdx.x;
  const float* s; short* d; int ks;
  if (idx < 36864)                    { s = We1;           d = W1sw;          ks = 265; }
  else if ((idx -= 36864) < 36864)    { s = We1 + 33920;   d = W1sw + 36864;  ks = 265; }
  else if ((idx -= 36864) < 16384)    { s = We2;           d = W2sw;          ks = 128; }
  else if ((idx -= 16384) < 16384)    { s = We2 + 16384;   d = W2sw + 16384;  ks = 128; }
  else if ((idx -= 16384) < 32768)    { s = Wn1;           d = Wn1sw;         ks = 256; }
  else if ((idx -= 32768) < 32768)    { s = Wn1 + 32768;   d = Wn1sw + 32768; ks = 256; }
  else if ((idx -= 32768) < 16384)    { s = Wn2;           d = Wn2sw;         ks = 128; }
  else if ((idx -= 16384) < 16384)    { s = Wn2 + 16384;   d = Wn2sw + 16384; ks = 128; }
  else if ((idx -= 16384) < 36864)    { s = cW1;           d = cW1sw;         ks = 265; }
  else if ((idx -= 36864) < 16384)    { s = cW2;           d = cW2sw;         ks = 128; }
  else return;
  int kk = idx >> 12;
  int rem = idx & 4095;
  int n = rem >> 5, kw = rem & 31;
  int cp = kw >> 3, j = kw & 7;
  int c = cp ^ ((n >> 1) & 3);
  int k = kk * 32 + c * 8 + j;
  float v = (k < ks) ? s[k * 128 + n] : 0.f;
  d[idx] = (short)f2bf(v);
}

// ---------------- small prep kernels ----------------
__global__ void k_init_xb(const float* __restrict__ x, short* __restrict__ Anode) {
  int i = blockIdx.x * 256 + threadIdx.x;
  if (i < NN * HH) Anode[(i >> 7) * 256 + (i & 127)] = (short)f2bf(x[i]);
}
__global__ void k_nodeprep(const float* __restrict__ agg, short* __restrict__ Anode) {
  int i = blockIdx.x * 256 + threadIdx.x;
  if (i < NN * HH) Anode[(i >> 7) * 256 + 128 + (i & 127)] = (short)f2bf(agg[i] * 0.01f);
}
__global__ void k_edge_pre(const float* __restrict__ pos, const float* __restrict__ eattr,
                           const int* __restrict__ ei, short* __restrict__ eaPad,
                           float* __restrict__ nd) {
  int e = blockIdx.x * 256 + threadIdx.x;
  if (e >= NE) return;
  int r = ei[e], c = ei[NE + e];
  float dx = pos[r * 3 + 0] - pos[c * 3 + 0];
  float dy = pos[r * 3 + 1] - pos[c * 3 + 1];
  float dz = pos[r * 3 + 2] - pos[c * 3 + 2];
  float d2 = dx * dx + dy * dy + dz * dz;
  float inv = 1.f / (sqrtf(d2) + 1.f);   // NC = 1.0
  nd[e * 3 + 0] = dx * inv;
  nd[e * 3 + 1] = dy * inv;
  nd[e * 3 + 2] = dz * inv;
  union { unsigned short s[32]; uint4 v[4]; } buf;
  buf.s[0] = f2bf(d2);
#pragma unroll
  for (int j = 0; j < 8; ++j) buf.s[1 + j] = f2bf(eattr[e * 8 + j]);
#pragma unroll
  for (int j = 9; j < 32; ++j) buf.s[j] = 0;
  uint4* dst = (uint4*)(eaPad + (size_t)e * 32);
#pragma unroll
  for (int j = 0; j < 4; ++j) dst[j] = buf.v[j];
}
__global__ void k_pos_final(const float* __restrict__ pos, const float* __restrict__ mask,
                            const float* __restrict__ pagg, float* __restrict__ out) {
  int i = blockIdx.x * 256 + threadIdx.x;
  if (i < NN * 3) out[i] = pos[i] + pagg[i] * 0.01f * mask[i / 3];
}

// ---------------- fused edge/coord MLP GEMM ----------------
// COORD=0: m=silu(silu(he@W1+b1)@W2+b2); att=sigm(m@wred+batt); atomicAdd m*att into outAcc[row][chan]
// COORD=1: g=silu(silu(he@W1+b1)@W2+b2); phi=g@wred; atomicAdd nd*phi into outAcc[row][0..2]
template <int COORD>
__global__ __launch_bounds__(256) void k_edge_gemm(
    const short* __restrict__ Anode, const short* __restrict__ eaPad,
    const int* __restrict__ ei, const short* __restrict__ W1l, const short* __restrict__ W2l,
    const float* __restrict__ b1, const float* __restrict__ b2,
    const float* __restrict__ wred, const float* __restrict__ batt,
    const float* __restrict__ nd, float* outAcc) {
  __shared__ short A2s[4 * 4096];
  __shared__ short As[4096];
  __shared__ short Bs[4096];
  __shared__ float redp[128][2];
  __shared__ float redv[128];

  const int tid = threadIdx.x;
  const int lane = tid & 63;
  const int w = tid >> 6;
  const int ln = lane & 15, q = lane >> 4;
  const int wm = w >> 1, wn = w & 1;
  const int tile = blockIdx.x;

  int el[2], rowv[2], colv[2], kch[2];
#pragma unroll
  for (int j = 0; j < 2; ++j) {
    el[j] = w * 32 + j * 16 + (lane >> 2);
    int e = tile * 128 + el[j];
    rowv[j] = ei[e];
    colv[j] = ei[NE + e];
    kch[j] = (lane & 3) ^ ((el[j] >> 1) & 3);
  }

  f32x4 acc[4][4];
  const f32x4 zero4 = {0.f, 0.f, 0.f, 0.f};
#pragma unroll
  for (int mi = 0; mi < 4; ++mi)
#pragma unroll
    for (int ni = 0; ni < 4; ++ni) acc[mi][ni] = zero4;

  // -------- GEMM1: he[128x288] @ W1[288x128] --------
  for (int kk = 0; kk < 9; ++kk) {
    __syncthreads();
    // B: contiguous pre-swizzled weights, 2KB per wave
#pragma unroll
    for (int j = 0; j < 2; ++j)
      gll16(W1l + kk * 4096 + w * 1024 + j * 512 + lane * 8, Bs + w * 1024 + j * 512);
    // A: gather (x[row] | x[col] | eaPad)
#pragma unroll
    for (int j = 0; j < 2; ++j) {
      int k0 = kk * 32 + kch[j] * 8;
      const short* src;
      if (kk < 4)      src = Anode + (size_t)rowv[j] * 256 + k0;
      else if (kk < 8) src = Anode + (size_t)colv[j] * 256 + (k0 - 128);
      else             src = eaPad + (size_t)(tile * 128 + el[j]) * 32 + (k0 - 256);
      gll16(src, As + (w * 32 + j * 16) * 32);
    }
    __syncthreads();
    bf16x8 af[4], bfr[4];
#pragma unroll
    for (int i = 0; i < 4; ++i) af[i] = frag_ld(As, wm * 64 + i * 16 + ln, q);
#pragma unroll
    for (int i = 0; i < 4; ++i) bfr[i] = frag_ld(Bs, wn * 64 + i * 16 + ln, q);
#pragma unroll
    for (int mi = 0; mi < 4; ++mi)
#pragma unroll
      for (int ni = 0; ni < 4; ++ni)
        acc[mi][ni] = __builtin_amdgcn_mfma_f32_16x16x32_bf16(af[mi], bfr[ni], acc[mi][ni], 0, 0, 0);
  }

  // -------- epilogue1: silu(h1+b1) -> A2s (bf16, swizzled blocks) --------
  float b1v[4];
#pragma unroll
  for (int ni = 0; ni < 4; ++ni) b1v[ni] = b1[wn * 64 + ni * 16 + ln];
#pragma unroll
  for (int mi = 0; mi < 4; ++mi)
#pragma unroll
    for (int ni = 0; ni < 4; ++ni) {
      int chan = wn * 64 + ni * 16 + ln;
      int kkb = chan >> 5, c = (chan >> 3) & 3, jj = chan & 7;
#pragma unroll
      for (int r = 0; r < 4; ++r) {
        int m = wm * 64 + mi * 16 + q * 4 + r;
        float v = silu_f(acc[mi][ni][r] + b1v[ni]);
        A2s[kkb * 4096 + m * 32 + ((c ^ ((m >> 1) & 3)) * 8) + jj] = (short)f2bf(v);
      }
    }

  // -------- GEMM2: h1s[128x128] @ W2[128x128] --------
  f32x4 acc2[4][4];
#pragma unroll
  for (int mi = 0; mi < 4; ++mi)
#pragma unroll
    for (int ni = 0; ni < 4; ++ni) acc2[mi][ni] = zero4;
  for (int kk = 0; kk < 4; ++kk) {
    __syncthreads();   // also publishes A2s writes on first iter
#pragma unroll
    for (int j = 0; j < 2; ++j)
      gll16(W2l + kk * 4096 + w * 1024 + j * 512 + lane * 8, Bs + w * 1024 + j * 512);
    __syncthreads();
    bf16x8 af[4], bfr[4];
#pragma unroll
    for (int i = 0; i < 4; ++i) af[i] = frag_ld(A2s + kk * 4096, wm * 64 + i * 16 + ln, q);
#pragma unroll
    for (int i = 0; i < 4; ++i) bfr[i] = frag_ld(Bs, wn * 64 + i * 16 + ln, q);
#pragma unroll
    for (int mi = 0; mi < 4; ++mi)
#pragma unroll
      for (int ni = 0; ni < 4; ++ni)
        acc2[mi][ni] = __builtin_amdgcn_mfma_f32_16x16x32_bf16(af[mi], bfr[ni], acc2[mi][ni], 0, 0, 0);
  }

  // -------- epilogue2 --------
  float b2v[4], wv[4];
#pragma unroll
  for (int ni = 0; ni < 4; ++ni) {
    int chan = wn * 64 + ni * 16 + ln;
    b2v[ni] = b2[chan];
    wv[ni] = wred[chan];
  }
  float p[4][4];
#pragma unroll
  for (int mi = 0; mi < 4; ++mi)
#pragma unroll
    for (int r = 0; r < 4; ++r) p[mi][r] = 0.f;
#pragma unroll
  for (int mi = 0; mi < 4; ++mi)
#pragma unroll
    for (int ni = 0; ni < 4; ++ni)
#pragma unroll
      for (int r = 0; r < 4; ++r) {
        float v = silu_f(acc2[mi][ni][r] + b2v[ni]);
        acc2[mi][ni][r] = v;
        p[mi][r] += v * wv[ni];
      }
#pragma unroll
  for (int d = 1; d < 16; d <<= 1)
#pragma unroll
    for (int mi = 0; mi < 4; ++mi)
#pragma unroll
      for (int r = 0; r < 4; ++r) p[mi][r] += __shfl_xor(p[mi][r], d, 64);
  if (ln == 0) {
#pragma unroll
    for (int mi = 0; mi < 4; ++mi)
#pragma unroll
      for (int r = 0; r < 4; ++r) redp[wm * 64 + mi * 16 + q * 4 + r][wn] = p[mi][r];
  }
  __syncthreads();
  if (COORD == 0) {
    if (tid < 128) redv[tid] = sigm_f(redp[tid][0] + redp[tid][1] + batt[0]);
    __syncthreads();
#pragma unroll
    for (int mi = 0; mi < 4; ++mi)
#pragma unroll
      for (int r = 0; r < 4; ++r) {
        int m = wm * 64 + mi * 16 + q * 4 + r;
        float a = redv[m];
        int rw = ei[tile * 128 + m];
#pragma unroll
        for (int ni = 0; ni < 4; ++ni) {
          int chan = wn * 64 + ni * 16 + ln;
          atomicAdd(&outAcc[(size_t)rw * 128 + chan], acc2[mi][ni][r] * a);
        }
      }
  } else {
    if (tid < 128) {
      int e = tile * 128 + tid;
      float phi = redp[tid][0] + redp[tid][1];
      int rw = ei[e];
      atomicAdd(&outAcc[rw * 3 + 0], nd[e * 3 + 0] * phi);
      atomicAdd(&outAcc[rw * 3 + 1], nd[e * 3 + 1] * phi);
      atomicAdd(&outAcc[rw * 3 + 2], nd[e * 3 + 2] * phi);
    }
  }
}

// ---------------- node MLP GEMM (residual update) ----------------
__global__ __launch_bounds__(256) void k_node_gemm(
    short* Anode, const short* __restrict__ Wn1l, const short* __restrict__ Wn2l,
    const float* __restrict__ b1, const float* __restrict__ b2,
    const float* __restrict__ xres, float* __restrict__ xout) {
  __shared__ short A2s[4 * 4096];
  __shared__ short As[4096];
  __shared__ short Bs[4096];

  const int tid = threadIdx.x;
  const int lane = tid & 63;
  const int w = tid >> 6;
  const int ln = lane & 15, q = lane >> 4;
  const int wm = w >> 1, wn = w & 1;
  const int tile = blockIdx.x;

  int nl[2], nclamp[2], kch[2];
#pragma unroll
  for (int j = 0; j < 2; ++j) {
    nl[j] = w * 32 + j * 16 + (lane >> 2);
    int node = tile * 128 + nl[j];
    nclamp[j] = node < NN ? node : (NN - 1);
    kch[j] = (lane & 3) ^ ((nl[j] >> 1) & 3);
  }

  f32x4 acc[4][4];
  const f32x4 zero4 = {0.f, 0.f, 0.f, 0.f};
#pragma unroll
  for (int mi = 0; mi < 4; ++mi)
#pragma unroll
    for (int ni = 0; ni < 4; ++ni) acc[mi][ni] = zero4;

  for (int kk = 0; kk < 8; ++kk) {
    __syncthreads();
#pragma unroll
    for (int j = 0; j < 2; ++j)
      gll16(Wn1l + kk * 4096 + w * 1024 + j * 512 + lane * 8, Bs + w * 1024 + j * 512);
#pragma unroll
    for (int j = 0; j < 2; ++j)
      gll16(Anode + (size_t)nclamp[j] * 256 + kk * 32 + kch[j] * 8, As + (w * 32 + j * 16) * 32);
    __syncthreads();
    bf16x8 af[4], bfr[4];
#pragma unroll
    for (int i = 0; i < 4; ++i) af[i] = frag_ld(As, wm * 64 + i * 16 + ln, q);
#pragma unroll
    for (int i = 0; i < 4; ++i) bfr[i] = frag_ld(Bs, wn * 64 + i * 16 + ln, q);
#pragma unroll
    for (int mi = 0; mi < 4; ++mi)
#pragma unroll
      for (int ni = 0; ni < 4; ++ni)
        acc[mi][ni] = __builtin_amdgcn_mfma_f32_16x16x32_bf16(af[mi], bfr[ni], acc[mi][ni], 0, 0, 0);
  }

  float b1v[4];
#pragma unroll
  for (int ni = 0; ni < 4; ++ni) b1v[ni] = b1[wn * 64 + ni * 16 + ln];
#pragma unroll
  for (int mi = 0; mi < 4; ++mi)
#pragma unroll
    for (int ni = 0; ni < 4; ++ni) {
      int chan = wn * 64 + ni * 16 + ln;
      int kkb = chan >> 5, c = (chan >> 3) & 3, jj = chan & 7;
#pragma unroll
      for (int r = 0; r < 4; ++r) {
        int m = wm * 64 + mi * 16 + q * 4 + r;
        float v = silu_f(acc[mi][ni][r] + b1v[ni]);
        A2s[kkb * 4096 + m * 32 + ((c ^ ((m >> 1) & 3)) * 8) + jj] = (short)f2bf(v);
      }
    }

  f32x4 acc2[4][4];
#pragma unroll
  for (int mi = 0; mi < 4; ++mi)
#pragma unroll
    for (int ni = 0; ni < 4; ++ni) acc2[mi][ni] = zero4;
  for (int kk = 0; kk < 4; ++kk) {
    __syncthreads();
#pragma unroll
    for (int j = 0; j < 2; ++j)
      gll16(Wn2l + kk * 4096 + w * 1024 + j * 512 + lane * 8, Bs + w * 1024 + j * 512);
    __syncthreads();
    bf16x8 af[4], bfr[4];
#pragma unroll
    for (int i = 0; i < 4; ++i) af[i] = frag_ld(A2s + kk * 4096, wm * 64 + i * 16 + ln, q);
#pragma unroll
    for (int i = 0; i < 4; ++i) bfr[i] = frag_ld(Bs, wn * 64 + i * 16 + ln, q);
#pragma unroll
    for (int mi = 0; mi < 4; ++mi)
#pragma unroll
      for (int ni = 0; ni < 4; ++ni)
        acc2[mi][ni] = __builtin_amdgcn_mfma_f32_16x16x32_bf16(af[mi], bfr[ni], acc2[mi][ni], 0, 0, 0);
  }

  float b2v[4];
#pragma unroll
  for (int ni = 0; ni < 4; ++ni) b2v[ni] = b2[wn * 64 + ni * 16 + ln];
#pragma unroll
  for (int mi = 0; mi < 4; ++mi)
#pragma unroll
    for (int r = 0; r < 4; ++r) {
      int m = wm * 64 + mi * 16 + q * 4 + r;
      int node = tile * 128 + m;
      if (node < NN) {
#pragma unroll
        for (int ni = 0; ni < 4; ++ni) {
          int chan = wn * 64 + ni * 16 + ln;
          float v = acc2[mi][ni][r] + b2v[ni] + xres[(size_t)node * 128 + chan];
          xout[(size_t)node * 128 + chan] = v;
          Anode[(size_t)node * 256 + chan] = (short)f2bf(v);
        }
      }
    }
}

extern "C" void kernel_launch(void* const* d_in, const int* in_sizes, int n_in,
                              void* d_out, int out_size, void* d_ws, size_t ws_size,
                              hipStream_t stream) {
  const float* x    = (const float*)d_in[0];
  const float* pos  = (const float*)d_in[1];
  const float* mask = (const float*)d_in[2];
  const float* eattr= (const float*)d_in[3];
  const int*   ei   = (const int*)d_in[4];
  const float* We1  = (const float*)d_in[5];
  const float* be1  = (const float*)d_in[6];
  const float* We2  = (const float*)d_in[7];
  const float* be2  = (const float*)d_in[8];
  const float* Watt = (const float*)d_in[9];
  const float* batt = (const float*)d_in[10];
  const float* Wn1  = (const float*)d_in[11];
  const float* bn1  = (const float*)d_in[12];
  const float* Wn2  = (const float*)d_in[13];
  const float* bn2  = (const float*)d_in[14];
  const float* cW1  = (const float*)d_in[15];
  const float* cb1  = (const float*)d_in[16];
  const float* cW2  = (const float*)d_in[17];
  const float* cb2  = (const float*)d_in[18];
  const float* cW3  = (const float*)d_in[19];

  char* p = (char*)d_ws;
  auto carve = [&](size_t bytes) { char* r = p; p += (bytes + 511) & ~(size_t)511; return r; };
  short* Anode = (short*)carve((size_t)NN * 256 * 2);
  short* eaPad = (short*)carve((size_t)NE * 32 * 2);
  float* nd    = (float*)carve((size_t)NE * 3 * 4);
  float* agg   = (float*)carve((size_t)NN * 128 * 4);
  float* xcur  = (float*)carve((size_t)NN * 128 * 4);
  float* pagg  = (float*)carve((size_t)NN * 3 * 4);
  short* W1sw  = (short*)carve(2 * 36864 * 2);
  short* W2sw  = (short*)carve(2 * 16384 * 2);
  short* Wn1sw = (short*)carve(2 * 32768 * 2);
  short* Wn2sw = (short*)carve(2 * 16384 * 2);
  short* cW1sw = (short*)carve(36864 * 2);
  short* cW2sw = (short*)carve(16384 * 2);

  float* xout_f = (float*)d_out;        // N*128
  float* pout_f = xout_f + NN * 128;    // N*3

  k_prep_weights<<<1008, 256, 0, stream>>>(We1, We2, Wn1, Wn2, cW1, cW2,
                                           W1sw, W2sw, Wn1sw, Wn2sw, cW1sw, cW2sw);
  k_init_xb<<<25000, 256, 0, stream>>>(x, Anode);
  k_edge_pre<<<3125, 256, 0, stream>>>(pos, eattr, ei, eaPad, nd);

  for (int l = 0; l < 2; ++l) {
    hipMemsetAsync(agg, 0, (size_t)NN * 128 * 4, stream);
    k_edge_gemm<0><<<6250, 256, 0, stream>>>(Anode, eaPad, ei,
        W1sw + l * 36864, W2sw + l * 16384, be1 + l * 128, be2 + l * 128,
        Watt + l * 128, batt + l, (const float*)nullptr, agg);
    k_nodeprep<<<25000, 256, 0, stream>>>(agg, Anode);
    k_node_gemm<<<391, 256, 0, stream>>>(Anode,
        Wn1sw + l * 32768, Wn2sw + l * 16384, bn1 + l * 128, bn2 + l * 128,
        l == 0 ? x : xcur, l == 0 ? xcur : xout_f);
  }
  hipMemsetAsync(pagg, 0, (size_t)NN * 3 * 4, stream);
  k_edge_gemm<1><<<6250, 256, 0, stream>>>(Anode, eaPad, ei,
      cW1sw, cW2sw, cb1, cb2, cW3, (const float*)nullptr, nd, pagg);
  k_pos_final<<<587, 256, 0, stream>>>(pos, mask, pagg, pout_f);
}

// Round 2
// 1144.299 us; speedup vs baseline: 1.0668x; 1.0668x over previous
//
#include <hip/hip_runtime.h>
#include <hip/hip_bf16.h>
#include <stdint.h>

#define NN 50000
#define NE 800000
#define HH 128

typedef __bf16 bf16x8 __attribute__((ext_vector_type(8)));
typedef float  f32x4  __attribute__((ext_vector_type(4)));

__device__ __forceinline__ unsigned short f2bf(float f) {
  union { float f; uint32_t u; } v; v.f = f;
  uint32_t r = v.u + 0x7FFFu + ((v.u >> 16) & 1u);
  return (unsigned short)(r >> 16);
}
__device__ __forceinline__ float bf2f(unsigned short s) {
  union { uint32_t u; float f; } v; v.u = ((uint32_t)s) << 16; return v.f;
}
__device__ __forceinline__ float silu_f(float x) { return x / (1.f + __expf(-x)); }
__device__ __forceinline__ float sigm_f(float x) { return 1.f / (1.f + __expf(-x)); }

typedef const __attribute__((address_space(1))) void gvoid_t;
typedef __attribute__((address_space(3))) void lvoid_t;
// async global->LDS, 16B per lane; dst must be wave-uniform (HW adds lane*16)
__device__ __forceinline__ void gll16(const void* g, void* l) {
  __builtin_amdgcn_global_load_lds((gvoid_t*)g, (lvoid_t*)l, 16, 0, 0);
}

// GEMM LDS tiles: [128 rows][32 k] bf16 (8KB blocks), 16B chunk c stored at c ^ ((row>>1)&3)
__device__ __forceinline__ bf16x8 frag_ld(const short* blk, int row, int q) {
  int c = q ^ ((row >> 1) & 3);
  return *(const bf16x8*)(blk + row * 32 + c * 8);
}

// ---------------- weight prep: transpose to [kk][n][32k] swizzled bf16 ----------------
__global__ void k_prep_weights(const float* We1, const float* We2, const float* Wn1,
                               const float* Wn2, const float* cW1, const float* cW2,
                               short* W1sw, short* W2sw, short* Wn1sw, short* Wn2sw,
                               short* cW1sw, short* cW2sw) {
  int idx = blockIdx.x * 256 + threadIdx.x;
  const float* s; short* d; int ks;
  if (idx < 36864)                    { s = We1;           d = W1sw;          ks = 265; }
  else if ((idx -= 36864) < 36864)    { s = We1 + 33920;   d = W1sw + 36864;  ks = 265; }
  else if ((idx -= 36864) < 16384)    { s = We2;           d = W2sw;          ks = 128; }
  else if ((idx -= 16384) < 16384)    { s = We2 + 16384;   d = W2sw + 16384;  ks = 128; }
  else if ((idx -= 16384) < 32768)    { s = Wn1;           d = Wn1sw;         ks = 256; }
  else if ((idx -= 32768) < 32768)    { s = Wn1 + 32768;   d = Wn1sw + 32768; ks = 256; }
  else if ((idx -= 32768) < 16384)    { s = Wn2;           d = Wn2sw;         ks = 128; }
  else if ((idx -= 16384) < 16384)    { s = Wn2 + 16384;   d = Wn2sw + 16384; ks = 128; }
  else if ((idx -= 16384) < 36864)    { s = cW1;           d = cW1sw;         ks = 265; }
  else if ((idx -= 36864) < 16384)    { s = cW2;           d = cW2sw;         ks = 128; }
  else return;
  int kk = idx >> 12;
  int rem = idx & 4095;
  int n = rem >> 5, kw = rem & 31;
  int cp = kw >> 3, j = kw & 7;
  int c = cp ^ ((n >> 1) & 3);
  int k = kk * 32 + c * 8 + j;
  float v = (k < ks) ? s[k * 128 + n] : 0.f;
  d[idx] = (short)f2bf(v);
}

// ---------------- small prep kernels ----------------
__global__ void k_init_xb(const float* __restrict__ x, short* __restrict__ Anode) {
  int i = blockIdx.x * 256 + threadIdx.x;
  if (i < NN * HH) Anode[(i >> 7) * 256 + (i & 127)] = (short)f2bf(x[i]);
}
__global__ void k_nodeprep(const float* __restrict__ agg, short* __restrict__ Anode) {
  int i = blockIdx.x * 256 + threadIdx.x;
  if (i < NN * HH) Anode[(i >> 7) * 256 + 128 + (i & 127)] = (short)f2bf(agg[i] * 0.01f);
}
__global__ void k_edge_pre(const float* __restrict__ pos, const float* __restrict__ eattr,
                           const int* __restrict__ ei, short* __restrict__ eaPad,
                           float* __restrict__ nd) {
  int e = blockIdx.x * 256 + threadIdx.x;
  if (e >= NE) return;
  int r = ei[e], c = ei[NE + e];
  float dx = pos[r * 3 + 0] - pos[c * 3 + 0];
  float dy = pos[r * 3 + 1] - pos[c * 3 + 1];
  float dz = pos[r * 3 + 2] - pos[c * 3 + 2];
  float d2 = dx * dx + dy * dy + dz * dz;
  float inv = 1.f / (sqrtf(d2) + 1.f);   // NC = 1.0
  nd[e * 3 + 0] = dx * inv;
  nd[e * 3 + 1] = dy * inv;
  nd[e * 3 + 2] = dz * inv;
  union { unsigned short s[32]; uint4 v[4]; } buf;
  buf.s[0] = f2bf(d2);
#pragma unroll
  for (int j = 0; j < 8; ++j) buf.s[1 + j] = f2bf(eattr[e * 8 + j]);
#pragma unroll
  for (int j = 9; j < 32; ++j) buf.s[j] = 0;
  uint4* dst = (uint4*)(eaPad + (size_t)e * 32);
#pragma unroll
  for (int j = 0; j < 4; ++j) dst[j] = buf.v[j];
}
__global__ void k_pos_final(const float* __restrict__ pos, const float* __restrict__ mask,
                            const float* __restrict__ pagg, float* __restrict__ out) {
  int i = blockIdx.x * 256 + threadIdx.x;
  if (i < NN * 3) out[i] = pos[i] + pagg[i] * 0.01f * mask[i / 3];
}

// ---------------- CSR sort of edges by destination row ----------------
__global__ void k_hist(const int* __restrict__ ei, int* __restrict__ cnt) {
  int e = blockIdx.x * 256 + threadIdx.x;
  if (e < NE) atomicAdd(&cnt[ei[e]], 1);
}
__global__ void k_scan_block(const int* __restrict__ cnt, int* __restrict__ offs,
                             int* __restrict__ bsum) {
  __shared__ int s[256];
  int i = blockIdx.x * 256 + threadIdx.x;
  int v = (i < NN) ? cnt[i] : 0;
  s[threadIdx.x] = v;
  __syncthreads();
#pragma unroll
  for (int d = 1; d < 256; d <<= 1) {
    int t = (threadIdx.x >= d) ? s[threadIdx.x - d] : 0;
    __syncthreads();
    s[threadIdx.x] += t;
    __syncthreads();
  }
  if (i < NN) offs[i] = s[threadIdx.x] - v;
  if (threadIdx.x == 255) bsum[blockIdx.x] = s[255];
}
__global__ void k_scan_top(int* __restrict__ bsum) {
  __shared__ int s[256];
  int v = (threadIdx.x < 196) ? bsum[threadIdx.x] : 0;
  s[threadIdx.x] = v;
  __syncthreads();
#pragma unroll
  for (int d = 1; d < 256; d <<= 1) {
    int t = (threadIdx.x >= d) ? s[threadIdx.x - d] : 0;
    __syncthreads();
    s[threadIdx.x] += t;
    __syncthreads();
  }
  if (threadIdx.x < 196) bsum[threadIdx.x] = s[threadIdx.x] - v;
}
__global__ void k_scan_add(int* __restrict__ offs, const int* __restrict__ bsum) {
  int i = blockIdx.x * 256 + threadIdx.x;
  if (i < NN) offs[i] += bsum[blockIdx.x];
}
__global__ void k_scatter(const int* __restrict__ ei, int* __restrict__ offs,
                          int* __restrict__ perm) {
  int e = blockIdx.x * 256 + threadIdx.x;
  if (e < NE) {
    int p = atomicAdd(&offs[ei[e]], 1);
    perm[p] = e;
  }
}

// ---------------- fused edge/coord MLP GEMM (edges presorted by row) ----------------
// COORD=0: m=silu(silu(he@W1+b1)@W2+b2); att=sigm(m@wred+batt); segment-sum m*att per row -> few atomics
// COORD=1: g=silu(silu(he@W1+b1)@W2+b2); phi=g@wred; segment-sum nd*phi per row -> few atomics
template <int COORD>
__global__ __launch_bounds__(256) void k_edge_gemm(
    const short* __restrict__ Anode, const short* __restrict__ eaPad,
    const int* __restrict__ ei, const int* __restrict__ perm,
    const short* __restrict__ W1l, const short* __restrict__ W2l,
    const float* __restrict__ b1, const float* __restrict__ b2,
    const float* __restrict__ wred, const float* __restrict__ batt,
    const float* __restrict__ nd, float* outAcc) {
  __shared__ short A2s[128 * 130];   // GEMM2 A-tile (first 16384) then C-tile [m][chan] stride 130
  __shared__ short As[4096];
  __shared__ short Bs[4096];
  __shared__ float redp[128][2];
  __shared__ float redv[128];
  __shared__ int srow[128];
  __shared__ int eorg[128];
  __shared__ float ndl[128][3];

  const int tid = threadIdx.x;
  const int lane = tid & 63;
  const int w = tid >> 6;
  const int ln = lane & 15, q = lane >> 4;
  const int wm = w >> 1, wn = w & 1;
  const int tile = blockIdx.x;

  if (tid < 128) {
    int eo = perm[tile * 128 + tid];
    eorg[tid] = eo;
    srow[tid] = ei[eo];
  }
  __syncthreads();

  int el[2], rowv[2], colv[2], kch[2], eo2[2];
#pragma unroll
  for (int j = 0; j < 2; ++j) {
    el[j] = w * 32 + j * 16 + (lane >> 2);
    int eo = eorg[el[j]];
    eo2[j] = eo;
    rowv[j] = srow[el[j]];
    colv[j] = ei[NE + eo];
    kch[j] = (lane & 3) ^ ((el[j] >> 1) & 3);
  }

  f32x4 acc[4][4];
  const f32x4 zero4 = {0.f, 0.f, 0.f, 0.f};
#pragma unroll
  for (int mi = 0; mi < 4; ++mi)
#pragma unroll
    for (int ni = 0; ni < 4; ++ni) acc[mi][ni] = zero4;

  // -------- GEMM1: he[128x288] @ W1[288x128] --------
  for (int kk = 0; kk < 9; ++kk) {
    __syncthreads();
#pragma unroll
    for (int j = 0; j < 2; ++j)
      gll16(W1l + kk * 4096 + w * 1024 + j * 512 + lane * 8, Bs + w * 1024 + j * 512);
#pragma unroll
    for (int j = 0; j < 2; ++j) {
      int k0 = kk * 32 + kch[j] * 8;
      const short* src;
      if (kk < 4)      src = Anode + (size_t)rowv[j] * 256 + k0;
      else if (kk < 8) src = Anode + (size_t)colv[j] * 256 + (k0 - 128);
      else             src = eaPad + (size_t)eo2[j] * 32 + (k0 - 256);
      gll16(src, As + (w * 32 + j * 16) * 32);
    }
    __syncthreads();
    bf16x8 af[4], bfr[4];
#pragma unroll
    for (int i = 0; i < 4; ++i) af[i] = frag_ld(As, wm * 64 + i * 16 + ln, q);
#pragma unroll
    for (int i = 0; i < 4; ++i) bfr[i] = frag_ld(Bs, wn * 64 + i * 16 + ln, q);
#pragma unroll
    for (int mi = 0; mi < 4; ++mi)
#pragma unroll
      for (int ni = 0; ni < 4; ++ni)
        acc[mi][ni] = __builtin_amdgcn_mfma_f32_16x16x32_bf16(af[mi], bfr[ni], acc[mi][ni], 0, 0, 0);
  }

  // -------- epilogue1: silu(h1+b1) -> A2s (bf16, swizzled blocks) --------
  float b1v[4];
#pragma unroll
  for (int ni = 0; ni < 4; ++ni) b1v[ni] = b1[wn * 64 + ni * 16 + ln];
#pragma unroll
  for (int mi = 0; mi < 4; ++mi)
#pragma unroll
    for (int ni = 0; ni < 4; ++ni) {
      int chan = wn * 64 + ni * 16 + ln;
      int kkb = chan >> 5, c = (chan >> 3) & 3, jj = chan & 7;
#pragma unroll
      for (int r = 0; r < 4; ++r) {
        int m = wm * 64 + mi * 16 + q * 4 + r;
        float v = silu_f(acc[mi][ni][r] + b1v[ni]);
        A2s[kkb * 4096 + m * 32 + ((c ^ ((m >> 1) & 3)) * 8) + jj] = (short)f2bf(v);
      }
    }

  // -------- GEMM2: h1s[128x128] @ W2[128x128] --------
  f32x4 acc2[4][4];
#pragma unroll
  for (int mi = 0; mi < 4; ++mi)
#pragma unroll
    for (int ni = 0; ni < 4; ++ni) acc2[mi][ni] = zero4;
  for (int kk = 0; kk < 4; ++kk) {
    __syncthreads();
#pragma unroll
    for (int j = 0; j < 2; ++j)
      gll16(W2l + kk * 4096 + w * 1024 + j * 512 + lane * 8, Bs + w * 1024 + j * 512);
    __syncthreads();
    bf16x8 af[4], bfr[4];
#pragma unroll
    for (int i = 0; i < 4; ++i) af[i] = frag_ld(A2s + kk * 4096, wm * 64 + i * 16 + ln, q);
#pragma unroll
    for (int i = 0; i < 4; ++i) bfr[i] = frag_ld(Bs, wn * 64 + i * 16 + ln, q);
#pragma unroll
    for (int mi = 0; mi < 4; ++mi)
#pragma unroll
      for (int ni = 0; ni < 4; ++ni)
        acc2[mi][ni] = __builtin_amdgcn_mfma_f32_16x16x32_bf16(af[mi], bfr[ni], acc2[mi][ni], 0, 0, 0);
  }

  // -------- epilogue2: silu + attention/phi reduce --------
  float b2v[4], wv[4];
#pragma unroll
  for (int ni = 0; ni < 4; ++ni) {
    int chan = wn * 64 + ni * 16 + ln;
    b2v[ni] = b2[chan];
    wv[ni] = wred[chan];
  }
  float p[4][4];
#pragma unroll
  for (int mi = 0; mi < 4; ++mi)
#pragma unroll
    for (int r = 0; r < 4; ++r) p[mi][r] = 0.f;
#pragma unroll
  for (int mi = 0; mi < 4; ++mi)
#pragma unroll
    for (int ni = 0; ni < 4; ++ni)
#pragma unroll
      for (int r = 0; r < 4; ++r) {
        float v = silu_f(acc2[mi][ni][r] + b2v[ni]);
        acc2[mi][ni][r] = v;
        p[mi][r] += v * wv[ni];
      }
#pragma unroll
  for (int d = 1; d < 16; d <<= 1)
#pragma unroll
    for (int mi = 0; mi < 4; ++mi)
#pragma unroll
      for (int r = 0; r < 4; ++r) p[mi][r] += __shfl_xor(p[mi][r], d, 64);
  __syncthreads();   // all waves done reading A2s (GEMM2) before we overwrite it with C
  if (ln == 0) {
#pragma unroll
    for (int mi = 0; mi < 4; ++mi)
#pragma unroll
      for (int r = 0; r < 4; ++r) redp[wm * 64 + mi * 16 + q * 4 + r][wn] = p[mi][r];
  }
  __syncthreads();

  if (COORD == 0) {
    if (tid < 128) redv[tid] = sigm_f(redp[tid][0] + redp[tid][1] + batt[0]);
    __syncthreads();
    // store att-scaled messages as bf16 C-tile [m][chan], stride 130 (bank-friendly)
#pragma unroll
    for (int mi = 0; mi < 4; ++mi)
#pragma unroll
      for (int ni = 0; ni < 4; ++ni) {
        int chan = wn * 64 + ni * 16 + ln;
#pragma unroll
        for (int r = 0; r < 4; ++r) {
          int m = wm * 64 + mi * 16 + q * 4 + r;
          A2s[m * 130 + chan] = (short)f2bf(acc2[mi][ni][r] * redv[m]);
        }
      }
    __syncthreads();
    // segmented sum over sorted rows: one atomic per (run, chan)
    int chan = tid & 127, half = tid >> 7;
    float sum = 0.f;
    int cur = srow[half * 64];
    for (int i = 0; i < 64; ++i) {
      int m = half * 64 + i;
      int rr = srow[m];
      if (rr != cur) {
        atomicAdd(&outAcc[(size_t)cur * 128 + chan], sum);
        sum = 0.f;
        cur = rr;
      }
      sum += bf2f((unsigned short)A2s[m * 130 + chan]);
    }
    atomicAdd(&outAcc[(size_t)cur * 128 + chan], sum);
  } else {
    if (tid < 128) {
      int eo = eorg[tid];
      float phi = redp[tid][0] + redp[tid][1];
      ndl[tid][0] = nd[eo * 3 + 0] * phi;
      ndl[tid][1] = nd[eo * 3 + 1] * phi;
      ndl[tid][2] = nd[eo * 3 + 2] * phi;
    }
    __syncthreads();
    if (tid < 6) {
      int c = tid >> 1, half = tid & 1;
      float sum = 0.f;
      int cur = srow[half * 64];
      for (int i = 0; i < 64; ++i) {
        int m = half * 64 + i;
        int rr = srow[m];
        if (rr != cur) {
          atomicAdd(&outAcc[cur * 3 + c], sum);
          sum = 0.f;
          cur = rr;
        }
        sum += ndl[m][c];
      }
      atomicAdd(&outAcc[cur * 3 + c], sum);
    }
  }
}

// ---------------- node MLP GEMM (residual update) ----------------
__global__ __launch_bounds__(256) void k_node_gemm(
    short* Anode, const short* __restrict__ Wn1l, const short* __restrict__ Wn2l,
    const float* __restrict__ b1, const float* __restrict__ b2,
    const float* __restrict__ xres, float* __restrict__ xout) {
  __shared__ short A2s[4 * 4096];
  __shared__ short As[4096];
  __shared__ short Bs[4096];

  const int tid = threadIdx.x;
  const int lane = tid & 63;
  const int w = tid >> 6;
  const int ln = lane & 15, q = lane >> 4;
  const int wm = w >> 1, wn = w & 1;
  const int tile = blockIdx.x;

  int nl[2], nclamp[2], kch[2];
#pragma unroll
  for (int j = 0; j < 2; ++j) {
    nl[j] = w * 32 + j * 16 + (lane >> 2);
    int node = tile * 128 + nl[j];
    nclamp[j] = node < NN ? node : (NN - 1);
    kch[j] = (lane & 3) ^ ((nl[j] >> 1) & 3);
  }

  f32x4 acc[4][4];
  const f32x4 zero4 = {0.f, 0.f, 0.f, 0.f};
#pragma unroll
  for (int mi = 0; mi < 4; ++mi)
#pragma unroll
    for (int ni = 0; ni < 4; ++ni) acc[mi][ni] = zero4;

  for (int kk = 0; kk < 8; ++kk) {
    __syncthreads();
#pragma unroll
    for (int j = 0; j < 2; ++j)
      gll16(Wn1l + kk * 4096 + w * 1024 + j * 512 + lane * 8, Bs + w * 1024 + j * 512);
#pragma unroll
    for (int j = 0; j < 2; ++j)
      gll16(Anode + (size_t)nclamp[j] * 256 + kk * 32 + kch[j] * 8, As + (w * 32 + j * 16) * 32);
    __syncthreads();
    bf16x8 af[4], bfr[4];
#pragma unroll
    for (int i = 0; i < 4; ++i) af[i] = frag_ld(As, wm * 64 + i * 16 + ln, q);
#pragma unroll
    for (int i = 0; i < 4; ++i) bfr[i] = frag_ld(Bs, wn * 64 + i * 16 + ln, q);
#pragma unroll
    for (int mi = 0; mi < 4; ++mi)
#pragma unroll
      for (int ni = 0; ni < 4; ++ni)
        acc[mi][ni] = __builtin_amdgcn_mfma_f32_16x16x32_bf16(af[mi], bfr[ni], acc[mi][ni], 0, 0, 0);
  }

  float b1v[4];
#pragma unroll
  for (int ni = 0; ni < 4; ++ni) b1v[ni] = b1[wn * 64 + ni * 16 + ln];
#pragma unroll
  for (int mi = 0; mi < 4; ++mi)
#pragma unroll
    for (int ni = 0; ni < 4; ++ni) {
      int chan = wn * 64 + ni * 16 + ln;
      int kkb = chan >> 5, c = (chan >> 3) & 3, jj = chan & 7;
#pragma unroll
      for (int r = 0; r < 4; ++r) {
        int m = wm * 64 + mi * 16 + q * 4 + r;
        float v = silu_f(acc[mi][ni][r] + b1v[ni]);
        A2s[kkb * 4096 + m * 32 + ((c ^ ((m >> 1) & 3)) * 8) + jj] = (short)f2bf(v);
      }
    }

  f32x4 acc2[4][4];
#pragma unroll
  for (int mi = 0; mi < 4; ++mi)
#pragma unroll
    for (int ni = 0; ni < 4; ++ni) acc2[mi][ni] = zero4;
  for (int kk = 0; kk < 4; ++kk) {
    __syncthreads();
#pragma unroll
    for (int j = 0; j < 2; ++j)
      gll16(Wn2l + kk * 4096 + w * 1024 + j * 512 + lane * 8, Bs + w * 1024 + j * 512);
    __syncthreads();
    bf16x8 af[4], bfr[4];
#pragma unroll
    for (int i = 0; i < 4; ++i) af[i] = frag_ld(A2s + kk * 4096, wm * 64 + i * 16 + ln, q);
#pragma unroll
    for (int i = 0; i < 4; ++i) bfr[i] = frag_ld(Bs, wn * 64 + i * 16 + ln, q);
#pragma unroll
    for (int mi = 0; mi < 4; ++mi)
#pragma unroll
      for (int ni = 0; ni < 4; ++ni)
        acc2[mi][ni] = __builtin_amdgcn_mfma_f32_16x16x32_bf16(af[mi], bfr[ni], acc2[mi][ni], 0, 0, 0);
  }

  float b2v[4];
#pragma unroll
  for (int ni = 0; ni < 4; ++ni) b2v[ni] = b2[wn * 64 + ni * 16 + ln];
#pragma unroll
  for (int mi = 0; mi < 4; ++mi)
#pragma unroll
    for (int r = 0; r < 4; ++r) {
      int m = wm * 64 + mi * 16 + q * 4 + r;
      int node = tile * 128 + m;
      if (node < NN) {
#pragma unroll
        for (int ni = 0; ni < 4; ++ni) {
          int chan = wn * 64 + ni * 16 + ln;
          float v = acc2[mi][ni][r] + b2v[ni] + xres[(size_t)node * 128 + chan];
          xout[(size_t)node * 128 + chan] = v;
          Anode[(size_t)node * 256 + chan] = (short)f2bf(v);
        }
      }
    }
}

extern "C" void kernel_launch(void* const* d_in, const int* in_sizes, int n_in,
                              void* d_out, int out_size, void* d_ws, size_t ws_size,
                              hipStream_t stream) {
  const float* x    = (const float*)d_in[0];
  const float* pos  = (const float*)d_in[1];
  const float* mask = (const float*)d_in[2];
  const float* eattr= (const float*)d_in[3];
  const int*   ei   = (const int*)d_in[4];
  const float* We1  = (const float*)d_in[5];
  const float* be1  = (const float*)d_in[6];
  const float* We2  = (const float*)d_in[7];
  const float* be2  = (const float*)d_in[8];
  const float* Watt = (const float*)d_in[9];
  const float* batt = (const float*)d_in[10];
  const float* Wn1  = (const float*)d_in[11];
  const float* bn1  = (const float*)d_in[12];
  const float* Wn2  = (const float*)d_in[13];
  const float* bn2  = (const float*)d_in[14];
  const float* cW1  = (const float*)d_in[15];
  const float* cb1  = (const float*)d_in[16];
  const float* cW2  = (const float*)d_in[17];
  const float* cb2  = (const float*)d_in[18];
  const float* cW3  = (const float*)d_in[19];

  char* p = (char*)d_ws;
  auto carve = [&](size_t bytes) { char* r = p; p += (bytes + 511) & ~(size_t)511; return r; };
  short* Anode = (short*)carve((size_t)NN * 256 * 2);
  short* eaPad = (short*)carve((size_t)NE * 32 * 2);
  float* nd    = (float*)carve((size_t)NE * 3 * 4);
  float* agg   = (float*)carve((size_t)NN * 128 * 4);
  float* xcur  = (float*)carve((size_t)NN * 128 * 4);
  float* pagg  = (float*)carve((size_t)NN * 3 * 4);
  short* W1sw  = (short*)carve(2 * 36864 * 2);
  short* W2sw  = (short*)carve(2 * 16384 * 2);
  short* Wn1sw = (short*)carve(2 * 32768 * 2);
  short* Wn2sw = (short*)carve(2 * 16384 * 2);
  short* cW1sw = (short*)carve(36864 * 2);
  short* cW2sw = (short*)carve(16384 * 2);
  int*   cnt   = (int*)carve((size_t)NN * 4);
  int*   offs  = (int*)carve((size_t)NN * 4);
  int*   bsum  = (int*)carve(256 * 4);
  int*   perm  = (int*)carve((size_t)NE * 4);

  float* xout_f = (float*)d_out;        // N*128
  float* pout_f = xout_f + NN * 128;    // N*3

  k_prep_weights<<<1008, 256, 0, stream>>>(We1, We2, Wn1, Wn2, cW1, cW2,
                                           W1sw, W2sw, Wn1sw, Wn2sw, cW1sw, cW2sw);
  k_init_xb<<<25000, 256, 0, stream>>>(x, Anode);
  k_edge_pre<<<3125, 256, 0, stream>>>(pos, eattr, ei, eaPad, nd);

  // build row-sorted edge permutation (CSR order)
  hipMemsetAsync(cnt, 0, (size_t)NN * 4, stream);
  k_hist<<<3125, 256, 0, stream>>>(ei, cnt);
  k_scan_block<<<196, 256, 0, stream>>>(cnt, offs, bsum);
  k_scan_top<<<1, 256, 0, stream>>>(bsum);
  k_scan_add<<<196, 256, 0, stream>>>(offs, bsum);
  k_scatter<<<3125, 256, 0, stream>>>(ei, offs, perm);

  for (int l = 0; l < 2; ++l) {
    hipMemsetAsync(agg, 0, (size_t)NN * 128 * 4, stream);
    k_edge_gemm<0><<<6250, 256, 0, stream>>>(Anode, eaPad, ei, perm,
        W1sw + l * 36864, W2sw + l * 16384, be1 + l * 128, be2 + l * 128,
        Watt + l * 128, batt + l, (const float*)nullptr, agg);
    k_nodeprep<<<25000, 256, 0, stream>>>(agg, Anode);
    k_node_gemm<<<391, 256, 0, stream>>>(Anode,
        Wn1sw + l * 32768, Wn2sw + l * 16384, bn1 + l * 128, bn2 + l * 128,
        l == 0 ? x : xcur, l == 0 ? xcur : xout_f);
  }
  hipMemsetAsync(pagg, 0, (size_t)NN * 3 * 4, stream);
  k_edge_gemm<1><<<6250, 256, 0, stream>>>(Anode, eaPad, ei, perm,
      cW1sw, cW2sw, cb1, cb2, cW3, (const float*)nullptr, nd, pagg);
  k_pos_final<<<587, 256, 0, stream>>>(pos, mask, pagg, pout_f);
}

// Round 3
// 1044.232 us; speedup vs baseline: 1.1691x; 1.0958x over previous
//
#include <hip/hip_runtime.h>
#include <hip/hip_bf16.h>
#include <stdint.h>

#define NN 50000
#define NE 800000
#define HH 128

typedef __bf16 bf16x8 __attribute__((ext_vector_type(8)));
typedef float  f32x4  __attribute__((ext_vector_type(4)));

__device__ __forceinline__ unsigned short f2bf(float f) {
  union { float f; uint32_t u; } v; v.f = f;
  uint32_t r = v.u + 0x7FFFu + ((v.u >> 16) & 1u);
  return (unsigned short)(r >> 16);
}
__device__ __forceinline__ float silu_f(float x) { return x / (1.f + __expf(-x)); }
__device__ __forceinline__ float sigm_f(float x) { return 1.f / (1.f + __expf(-x)); }

typedef const __attribute__((address_space(1))) void gvoid_t;
typedef __attribute__((address_space(3))) void lvoid_t;
// async global->LDS, 16B per lane; dst must be wave-uniform (HW adds lane*16)
__device__ __forceinline__ void gll16(const void* g, void* l) {
  __builtin_amdgcn_global_load_lds((gvoid_t*)g, (lvoid_t*)l, 16, 0, 0);
}

// GEMM LDS tiles: [128 rows][32 k] bf16 (8KB blocks), 16B chunk c stored at c ^ ((row>>1)&3)
__device__ __forceinline__ bf16x8 frag_ld(const short* blk, int row, int q) {
  int c = q ^ ((row >> 1) & 3);
  return *(const bf16x8*)(blk + row * 32 + c * 8);
}

// ---------------- weight prep: transpose to [kk][n][32k] swizzled bf16 ----------------
__global__ void k_prep_weights(const float* We1, const float* We2, const float* Wn1,
                               const float* Wn2, const float* cW1, const float* cW2,
                               short* W1sw, short* W2sw, short* Wn1sw, short* Wn2sw,
                               short* cW1sw, short* cW2sw) {
  int idx = blockIdx.x * 256 + threadIdx.x;
  const float* s; short* d; int ks;
  if (idx < 36864)                    { s = We1;           d = W1sw;          ks = 265; }
  else if ((idx -= 36864) < 36864)    { s = We1 + 33920;   d = W1sw + 36864;  ks = 265; }
  else if ((idx -= 36864) < 16384)    { s = We2;           d = W2sw;          ks = 128; }
  else if ((idx -= 16384) < 16384)    { s = We2 + 16384;   d = W2sw + 16384;  ks = 128; }
  else if ((idx -= 16384) < 32768)    { s = Wn1;           d = Wn1sw;         ks = 256; }
  else if ((idx -= 32768) < 32768)    { s = Wn1 + 32768;   d = Wn1sw + 32768; ks = 256; }
  else if ((idx -= 32768) < 16384)    { s = Wn2;           d = Wn2sw;         ks = 128; }
  else if ((idx -= 16384) < 16384)    { s = Wn2 + 16384;   d = Wn2sw + 16384; ks = 128; }
  else if ((idx -= 16384) < 36864)    { s = cW1;           d = cW1sw;         ks = 265; }
  else if ((idx -= 36864) < 16384)    { s = cW2;           d = cW2sw;         ks = 128; }
  else return;
  int kk = idx >> 12;
  int rem = idx & 4095;
  int n = rem >> 5, kw = rem & 31;
  int cp = kw >> 3, j = kw & 7;
  int c = cp ^ ((n >> 1) & 3);
  int k = kk * 32 + c * 8 + j;
  float v = (k < ks) ? s[k * 128 + n] : 0.f;
  d[idx] = (short)f2bf(v);
}

// ---------------- small prep kernels ----------------
__global__ void k_init_xb(const float* __restrict__ x, short* __restrict__ Anode) {
  int i = blockIdx.x * 256 + threadIdx.x;
  if (i < NN * HH) Anode[(i >> 7) * 256 + (i & 127)] = (short)f2bf(x[i]);
}
__global__ void k_nodeprep(const float* __restrict__ agg, short* __restrict__ Anode) {
  int i = blockIdx.x * 256 + threadIdx.x;
  if (i < NN * HH) Anode[(i >> 7) * 256 + 128 + (i & 127)] = (short)f2bf(agg[i] * 0.01f);
}
__global__ void k_edge_pre(const float* __restrict__ pos, const float* __restrict__ eattr,
                           const int* __restrict__ ei, short* __restrict__ eaPad,
                           float* __restrict__ nd) {
  int e = blockIdx.x * 256 + threadIdx.x;
  if (e >= NE) return;
  int r = ei[e], c = ei[NE + e];
  float dx = pos[r * 3 + 0] - pos[c * 3 + 0];
  float dy = pos[r * 3 + 1] - pos[c * 3 + 1];
  float dz = pos[r * 3 + 2] - pos[c * 3 + 2];
  float d2 = dx * dx + dy * dy + dz * dz;
  float inv = 1.f / (sqrtf(d2) + 1.f);   // NC = 1.0
  nd[e * 3 + 0] = dx * inv;
  nd[e * 3 + 1] = dy * inv;
  nd[e * 3 + 2] = dz * inv;
  union { unsigned short s[32]; uint4 v[4]; } buf;
  buf.s[0] = f2bf(d2);
#pragma unroll
  for (int j = 0; j < 8; ++j) buf.s[1 + j] = f2bf(eattr[e * 8 + j]);
#pragma unroll
  for (int j = 9; j < 32; ++j) buf.s[j] = 0;
  uint4* dst = (uint4*)(eaPad + (size_t)e * 32);
#pragma unroll
  for (int j = 0; j < 4; ++j) dst[j] = buf.v[j];
}
__global__ void k_pos_final(const float* __restrict__ pos, const float* __restrict__ mask,
                            const float* __restrict__ pagg, float* __restrict__ out) {
  int i = blockIdx.x * 256 + threadIdx.x;
  if (i < NN * 3) out[i] = pos[i] + pagg[i] * 0.01f * mask[i / 3];
}

// ---------------- CSR sort of edges by destination row ----------------
__global__ void k_hist(const int* __restrict__ ei, int* __restrict__ cnt) {
  int e = blockIdx.x * 256 + threadIdx.x;
  if (e < NE) atomicAdd(&cnt[ei[e]], 1);
}
__global__ void k_scan_block(const int* __restrict__ cnt, int* __restrict__ offs,
                             int* __restrict__ bsum) {
  __shared__ int s[256];
  int i = blockIdx.x * 256 + threadIdx.x;
  int v = (i < NN) ? cnt[i] : 0;
  s[threadIdx.x] = v;
  __syncthreads();
#pragma unroll
  for (int d = 1; d < 256; d <<= 1) {
    int t = (threadIdx.x >= d) ? s[threadIdx.x - d] : 0;
    __syncthreads();
    s[threadIdx.x] += t;
    __syncthreads();
  }
  if (i < NN) offs[i] = s[threadIdx.x] - v;
  if (threadIdx.x == 255) bsum[blockIdx.x] = s[255];
}
__global__ void k_scan_top(int* __restrict__ bsum) {
  __shared__ int s[256];
  int v = (threadIdx.x < 196) ? bsum[threadIdx.x] : 0;
  s[threadIdx.x] = v;
  __syncthreads();
#pragma unroll
  for (int d = 1; d < 256; d <<= 1) {
    int t = (threadIdx.x >= d) ? s[threadIdx.x - d] : 0;
    __syncthreads();
    s[threadIdx.x] += t;
    __syncthreads();
  }
  if (threadIdx.x < 196) bsum[threadIdx.x] = s[threadIdx.x] - v;
}
__global__ void k_scan_add(int* __restrict__ offs, const int* __restrict__ bsum) {
  int i = blockIdx.x * 256 + threadIdx.x;
  if (i < NN) offs[i] += bsum[blockIdx.x];
}
__global__ void k_scatter(const int* __restrict__ ei, int* __restrict__ offs,
                          int* __restrict__ perm) {
  int e = blockIdx.x * 256 + threadIdx.x;
  if (e < NE) {
    int p = atomicAdd(&offs[ei[e]], 1);
    perm[p] = e;
  }
}

// ---------------- fused edge/coord MLP GEMM (edges presorted by row) ----------------
// COORD=0: m=silu(silu(he@W1+b1)@W2+b2); att=sigm(m@wred+batt);
//          agg[run][chan] = S^T @ (m*att) via MFMA (S = 0/1 segment matrix), few atomics
// COORD=1: g=silu(silu(he@W1+b1)@W2+b2); phi=g@wred; run-start walkers sum nd*phi, few atomics
template <int COORD>
__global__ __launch_bounds__(256) void k_edge_gemm(
    const short* __restrict__ Anode, const short* __restrict__ eaPad,
    const int* __restrict__ ei, const int* __restrict__ perm,
    const short* __restrict__ W1l, const short* __restrict__ W2l,
    const float* __restrict__ b1, const float* __restrict__ b2,
    const float* __restrict__ wred, const float* __restrict__ batt,
    const float* __restrict__ nd, float* outAcc) {
  __shared__ short A2s[4 * 4096];   // GEMM2 A-tile; then C-tile [chan][edge] swizzled (COORD=0) / ndl (COORD=1)
  __shared__ short As[4096];
  __shared__ short Bs[4096];
  __shared__ float redp[128][2];
  __shared__ float redv[128];
  __shared__ int srow[128];
  __shared__ int eorg[128];
  __shared__ __align__(8) unsigned char srunS[128];
  __shared__ int runrowS[128];
  __shared__ int cntS[2];

  const int tid = threadIdx.x;
  const int lane = tid & 63;
  const int w = tid >> 6;
  const int ln = lane & 15, q = lane >> 4;
  const int wm = w >> 1, wn = w & 1;
  const int tile = blockIdx.x;

  if (tid < 128) {
    int eo = perm[tile * 128 + tid];
    eorg[tid] = eo;
    srow[tid] = ei[eo];
  }
  __syncthreads();

  // ---- segmented-run scan over sorted rows (ballot prefix) ----
  bool is_start = (tid < 128) && (tid == 0 || srow[tid] != srow[tid - 1]);
  unsigned long long bmask = __ballot(is_start);
  int pre = __popcll(bmask & ((1ull << lane) - 1ull));
  if (tid < 128 && lane == 63) cntS[tid >> 6] = __popcll(bmask);
  __syncthreads();
  const int nruns = cntS[0] + cntS[1];
  if (tid < 128) {
    int run = pre + (is_start ? 1 : 0) - 1 + ((tid >= 64) ? cntS[0] : 0);
    srunS[tid] = (unsigned char)run;
    if (is_start) runrowS[run] = srow[tid];
  }
  // (writes published by the K-loop's first __syncthreads; read only after GEMM2)

  int el[2], rowv[2], colv[2], kch[2], eo2[2];
#pragma unroll
  for (int j = 0; j < 2; ++j) {
    el[j] = w * 32 + j * 16 + (lane >> 2);
    int eo = eorg[el[j]];
    eo2[j] = eo;
    rowv[j] = srow[el[j]];
    colv[j] = ei[NE + eo];
    kch[j] = (lane & 3) ^ ((el[j] >> 1) & 3);
  }

  f32x4 acc[4][4];
  const f32x4 zero4 = {0.f, 0.f, 0.f, 0.f};
#pragma unroll
  for (int mi = 0; mi < 4; ++mi)
#pragma unroll
    for (int ni = 0; ni < 4; ++ni) acc[mi][ni] = zero4;

  // -------- GEMM1: he[128x288] @ W1[288x128] --------
  for (int kk = 0; kk < 9; ++kk) {
    __syncthreads();
#pragma unroll
    for (int j = 0; j < 2; ++j)
      gll16(W1l + kk * 4096 + w * 1024 + j * 512 + lane * 8, Bs + w * 1024 + j * 512);
#pragma unroll
    for (int j = 0; j < 2; ++j) {
      int k0 = kk * 32 + kch[j] * 8;
      const short* src;
      if (kk < 4)      src = Anode + (size_t)rowv[j] * 256 + k0;
      else if (kk < 8) src = Anode + (size_t)colv[j] * 256 + (k0 - 128);
      else             src = eaPad + (size_t)eo2[j] * 32 + (k0 - 256);
      gll16(src, As + (w * 32 + j * 16) * 32);
    }
    __syncthreads();
    bf16x8 af[4], bfr[4];
#pragma unroll
    for (int i = 0; i < 4; ++i) af[i] = frag_ld(As, wm * 64 + i * 16 + ln, q);
#pragma unroll
    for (int i = 0; i < 4; ++i) bfr[i] = frag_ld(Bs, wn * 64 + i * 16 + ln, q);
#pragma unroll
    for (int mi = 0; mi < 4; ++mi)
#pragma unroll
      for (int ni = 0; ni < 4; ++ni)
        acc[mi][ni] = __builtin_amdgcn_mfma_f32_16x16x32_bf16(af[mi], bfr[ni], acc[mi][ni], 0, 0, 0);
  }

  // -------- epilogue1: silu(h1+b1) -> A2s (bf16, swizzled blocks) --------
  float b1v[4];
#pragma unroll
  for (int ni = 0; ni < 4; ++ni) b1v[ni] = b1[wn * 64 + ni * 16 + ln];
#pragma unroll
  for (int mi = 0; mi < 4; ++mi)
#pragma unroll
    for (int ni = 0; ni < 4; ++ni) {
      int chan = wn * 64 + ni * 16 + ln;
      int kkb = chan >> 5, c = (chan >> 3) & 3, jj = chan & 7;
#pragma unroll
      for (int r = 0; r < 4; ++r) {
        int m = wm * 64 + mi * 16 + q * 4 + r;
        float v = silu_f(acc[mi][ni][r] + b1v[ni]);
        A2s[kkb * 4096 + m * 32 + ((c ^ ((m >> 1) & 3)) * 8) + jj] = (short)f2bf(v);
      }
    }

  // -------- GEMM2: h1s[128x128] @ W2[128x128] --------
  f32x4 acc2[4][4];
#pragma unroll
  for (int mi = 0; mi < 4; ++mi)
#pragma unroll
    for (int ni = 0; ni < 4; ++ni) acc2[mi][ni] = zero4;
  for (int kk = 0; kk < 4; ++kk) {
    __syncthreads();   // also publishes A2s writes on first iter
#pragma unroll
    for (int j = 0; j < 2; ++j)
      gll16(W2l + kk * 4096 + w * 1024 + j * 512 + lane * 8, Bs + w * 1024 + j * 512);
    __syncthreads();
    bf16x8 af[4], bfr[4];
#pragma unroll
    for (int i = 0; i < 4; ++i) af[i] = frag_ld(A2s + kk * 4096, wm * 64 + i * 16 + ln, q);
#pragma unroll
    for (int i = 0; i < 4; ++i) bfr[i] = frag_ld(Bs, wn * 64 + i * 16 + ln, q);
#pragma unroll
    for (int mi = 0; mi < 4; ++mi)
#pragma unroll
      for (int ni = 0; ni < 4; ++ni)
        acc2[mi][ni] = __builtin_amdgcn_mfma_f32_16x16x32_bf16(af[mi], bfr[ni], acc2[mi][ni], 0, 0, 0);
  }

  // -------- epilogue2: silu + attention/phi reduce --------
  float b2v[4], wv[4];
#pragma unroll
  for (int ni = 0; ni < 4; ++ni) {
    int chan = wn * 64 + ni * 16 + ln;
    b2v[ni] = b2[chan];
    wv[ni] = wred[chan];
  }
  float p[4][4];
#pragma unroll
  for (int mi = 0; mi < 4; ++mi)
#pragma unroll
    for (int r = 0; r < 4; ++r) p[mi][r] = 0.f;
#pragma unroll
  for (int mi = 0; mi < 4; ++mi)
#pragma unroll
    for (int ni = 0; ni < 4; ++ni)
#pragma unroll
      for (int r = 0; r < 4; ++r) {
        float v = silu_f(acc2[mi][ni][r] + b2v[ni]);
        acc2[mi][ni][r] = v;
        p[mi][r] += v * wv[ni];
      }
#pragma unroll
  for (int d = 1; d < 16; d <<= 1)
#pragma unroll
    for (int mi = 0; mi < 4; ++mi)
#pragma unroll
      for (int r = 0; r < 4; ++r) p[mi][r] += __shfl_xor(p[mi][r], d, 64);
  __syncthreads();   // all waves done reading A2s (GEMM2) before we overwrite it
  if (ln == 0) {
#pragma unroll
    for (int mi = 0; mi < 4; ++mi)
#pragma unroll
      for (int r = 0; r < 4; ++r) redp[wm * 64 + mi * 16 + q * 4 + r][wn] = p[mi][r];
  }
  __syncthreads();

  if (COORD == 0) {
    if (tid < 128) redv[tid] = sigm_f(redp[tid][0] + redp[tid][1] + batt[0]);
    __syncthreads();
    // C-tile in [chan][edge] chunk-swizzled blocks: B-operand layout for the S-GEMM
#pragma unroll
    for (int mi = 0; mi < 4; ++mi)
#pragma unroll
      for (int ni = 0; ni < 4; ++ni) {
        int chan = wn * 64 + ni * 16 + ln;
#pragma unroll
        for (int r = 0; r < 4; ++r) {
          int m = wm * 64 + mi * 16 + q * 4 + r;
          A2s[(m >> 5) * 4096 + chan * 32 + ((((m >> 3) & 3) ^ ((chan >> 1) & 3)) * 8) + (m & 7)]
              = (short)f2bf(acc2[mi][ni][r] * redv[m]);
        }
      }
    __syncthreads();
    // segment-sum via MFMA: agg[run][chan] = S[run][edge] @ M[edge][chan]
    bf16x8 bfrg[4][2];
#pragma unroll
    for (int kk = 0; kk < 4; ++kk)
#pragma unroll
      for (int ni = 0; ni < 2; ++ni)
        bfrg[kk][ni] = frag_ld(A2s + kk * 4096, w * 32 + ni * 16 + ln, q);
    const int npass = (nruns + 15) >> 4;
    for (int pp = 0; pp < npass; ++pp) {
      const unsigned int base = pp * 16;
      f32x4 a3[2] = {zero4, zero4};
#pragma unroll
      for (int kk = 0; kk < 4; ++kk) {
        uint2 sb = *(const uint2*)(srunS + kk * 32 + q * 8);
        union { short s[8]; bf16x8 v; } af;
#pragma unroll
        for (int j = 0; j < 4; ++j)
          af.s[j] = (((sb.x >> (8 * j)) & 255u) == base + (unsigned)ln) ? (short)0x3F80 : (short)0;
#pragma unroll
        for (int j = 0; j < 4; ++j)
          af.s[4 + j] = (((sb.y >> (8 * j)) & 255u) == base + (unsigned)ln) ? (short)0x3F80 : (short)0;
        a3[0] = __builtin_amdgcn_mfma_f32_16x16x32_bf16(af.v, bfrg[kk][0], a3[0], 0, 0, 0);
        a3[1] = __builtin_amdgcn_mfma_f32_16x16x32_bf16(af.v, bfrg[kk][1], a3[1], 0, 0, 0);
      }
#pragma unroll
      for (int ni = 0; ni < 2; ++ni)
#pragma unroll
        for (int r = 0; r < 4; ++r) {
          int run = (int)base + q * 4 + r;
          if (run < nruns) {
            int rw = runrowS[run];
            atomicAdd(&outAcc[(size_t)rw * 128 + (w * 32 + ni * 16 + ln)], a3[ni][r]);
          }
        }
    }
  } else {
    float* ndl = (float*)A2s;   // reuse: [128][3]
    if (tid < 128) {
      int eo = eorg[tid];
      float phi = redp[tid][0] + redp[tid][1];
      ndl[tid * 3 + 0] = nd[eo * 3 + 0] * phi;
      ndl[tid * 3 + 1] = nd[eo * 3 + 1] * phi;
      ndl[tid * 3 + 2] = nd[eo * 3 + 2] * phi;
    }
    __syncthreads();
    if (is_start) {   // run-start walkers (tid<128 implied)
      int myrow = srow[tid];
      float s0 = 0.f, s1 = 0.f, s2 = 0.f;
      for (int j = tid; j < 128 && srow[j] == myrow; ++j) {
        s0 += ndl[j * 3 + 0];
        s1 += ndl[j * 3 + 1];
        s2 += ndl[j * 3 + 2];
      }
      atomicAdd(&outAcc[myrow * 3 + 0], s0);
      atomicAdd(&outAcc[myrow * 3 + 1], s1);
      atomicAdd(&outAcc[myrow * 3 + 2], s2);
    }
  }
}

// ---------------- node MLP GEMM (residual update) ----------------
__global__ __launch_bounds__(256) void k_node_gemm(
    short* Anode, const short* __restrict__ Wn1l, const short* __restrict__ Wn2l,
    const float* __restrict__ b1, const float* __restrict__ b2,
    const float* __restrict__ xres, float* __restrict__ xout) {
  __shared__ short A2s[4 * 4096];
  __shared__ short As[4096];
  __shared__ short Bs[4096];

  const int tid = threadIdx.x;
  const int lane = tid & 63;
  const int w = tid >> 6;
  const int ln = lane & 15, q = lane >> 4;
  const int wm = w >> 1, wn = w & 1;
  const int tile = blockIdx.x;

  int nl[2], nclamp[2], kch[2];
#pragma unroll
  for (int j = 0; j < 2; ++j) {
    nl[j] = w * 32 + j * 16 + (lane >> 2);
    int node = tile * 128 + nl[j];
    nclamp[j] = node < NN ? node : (NN - 1);
    kch[j] = (lane & 3) ^ ((nl[j] >> 1) & 3);
  }

  f32x4 acc[4][4];
  const f32x4 zero4 = {0.f, 0.f, 0.f, 0.f};
#pragma unroll
  for (int mi = 0; mi < 4; ++mi)
#pragma unroll
    for (int ni = 0; ni < 4; ++ni) acc[mi][ni] = zero4;

  for (int kk = 0; kk < 8; ++kk) {
    __syncthreads();
#pragma unroll
    for (int j = 0; j < 2; ++j)
      gll16(Wn1l + kk * 4096 + w * 1024 + j * 512 + lane * 8, Bs + w * 1024 + j * 512);
#pragma unroll
    for (int j = 0; j < 2; ++j)
      gll16(Anode + (size_t)nclamp[j] * 256 + kk * 32 + kch[j] * 8, As + (w * 32 + j * 16) * 32);
    __syncthreads();
    bf16x8 af[4], bfr[4];
#pragma unroll
    for (int i = 0; i < 4; ++i) af[i] = frag_ld(As, wm * 64 + i * 16 + ln, q);
#pragma unroll
    for (int i = 0; i < 4; ++i) bfr[i] = frag_ld(Bs, wn * 64 + i * 16 + ln, q);
#pragma unroll
    for (int mi = 0; mi < 4; ++mi)
#pragma unroll
      for (int ni = 0; ni < 4; ++ni)
        acc[mi][ni] = __builtin_amdgcn_mfma_f32_16x16x32_bf16(af[mi], bfr[ni], acc[mi][ni], 0, 0, 0);
  }

  float b1v[4];
#pragma unroll
  for (int ni = 0; ni < 4; ++ni) b1v[ni] = b1[wn * 64 + ni * 16 + ln];
#pragma unroll
  for (int mi = 0; mi < 4; ++mi)
#pragma unroll
    for (int ni = 0; ni < 4; ++ni) {
      int chan = wn * 64 + ni * 16 + ln;
      int kkb = chan >> 5, c = (chan >> 3) & 3, jj = chan & 7;
#pragma unroll
      for (int r = 0; r < 4; ++r) {
        int m = wm * 64 + mi * 16 + q * 4 + r;
        float v = silu_f(acc[mi][ni][r] + b1v[ni]);
        A2s[kkb * 4096 + m * 32 + ((c ^ ((m >> 1) & 3)) * 8) + jj] = (short)f2bf(v);
      }
    }

  f32x4 acc2[4][4];
#pragma unroll
  for (int mi = 0; mi < 4; ++mi)
#pragma unroll
    for (int ni = 0; ni < 4; ++ni) acc2[mi][ni] = zero4;
  for (int kk = 0; kk < 4; ++kk) {
    __syncthreads();
#pragma unroll
    for (int j = 0; j < 2; ++j)
      gll16(Wn2l + kk * 4096 + w * 1024 + j * 512 + lane * 8, Bs + w * 1024 + j * 512);
    __syncthreads();
    bf16x8 af[4], bfr[4];
#pragma unroll
    for (int i = 0; i < 4; ++i) af[i] = frag_ld(A2s + kk * 4096, wm * 64 + i * 16 + ln, q);
#pragma unroll
    for (int i = 0; i < 4; ++i) bfr[i] = frag_ld(Bs, wn * 64 + i * 16 + ln, q);
#pragma unroll
    for (int mi = 0; mi < 4; ++mi)
#pragma unroll
      for (int ni = 0; ni < 4; ++ni)
        acc2[mi][ni] = __builtin_amdgcn_mfma_f32_16x16x32_bf16(af[mi], bfr[ni], acc2[mi][ni], 0, 0, 0);
  }

  float b2v[4];
#pragma unroll
  for (int ni = 0; ni < 4; ++ni) b2v[ni] = b2[wn * 64 + ni * 16 + ln];
#pragma unroll
  for (int mi = 0; mi < 4; ++mi)
#pragma unroll
    for (int r = 0; r < 4; ++r) {
      int m = wm * 64 + mi * 16 + q * 4 + r;
      int node = tile * 128 + m;
      if (node < NN) {
#pragma unroll
        for (int ni = 0; ni < 4; ++ni) {
          int chan = wn * 64 + ni * 16 + ln;
          float v = acc2[mi][ni][r] + b2v[ni] + xres[(size_t)node * 128 + chan];
          xout[(size_t)node * 128 + chan] = v;
          Anode[(size_t)node * 256 + chan] = (short)f2bf(v);
        }
      }
    }
}

extern "C" void kernel_launch(void* const* d_in, const int* in_sizes, int n_in,
                              void* d_out, int out_size, void* d_ws, size_t ws_size,
                              hipStream_t stream) {
  const float* x    = (const float*)d_in[0];
  const float* pos  = (const float*)d_in[1];
  const float* mask = (const float*)d_in[2];
  const float* eattr= (const float*)d_in[3];
  const int*   ei   = (const int*)d_in[4];
  const float* We1  = (const float*)d_in[5];
  const float* be1  = (const float*)d_in[6];
  const float* We2  = (const float*)d_in[7];
  const float* be2  = (const float*)d_in[8];
  const float* Watt = (const float*)d_in[9];
  const float* batt = (const float*)d_in[10];
  const float* Wn1  = (const float*)d_in[11];
  const float* bn1  = (const float*)d_in[12];
  const float* Wn2  = (const float*)d_in[13];
  const float* bn2  = (const float*)d_in[14];
  const float* cW1  = (const float*)d_in[15];
  const float* cb1  = (const float*)d_in[16];
  const float* cW2  = (const float*)d_in[17];
  const float* cb2  = (const float*)d_in[18];
  const float* cW3  = (const float*)d_in[19];

  char* p = (char*)d_ws;
  auto carve = [&](size_t bytes) { char* r = p; p += (bytes + 511) & ~(size_t)511; return r; };
  short* Anode = (short*)carve((size_t)NN * 256 * 2);
  short* eaPad = (short*)carve((size_t)NE * 32 * 2);
  float* nd    = (float*)carve((size_t)NE * 3 * 4);
  float* agg   = (float*)carve((size_t)NN * 128 * 4);
  float* xcur  = (float*)carve((size_t)NN * 128 * 4);
  float* pagg  = (float*)carve((size_t)NN * 3 * 4);
  short* W1sw  = (short*)carve(2 * 36864 * 2);
  short* W2sw  = (short*)carve(2 * 16384 * 2);
  short* Wn1sw = (short*)carve(2 * 32768 * 2);
  short* Wn2sw = (short*)carve(2 * 16384 * 2);
  short* cW1sw = (short*)carve(36864 * 2);
  short* cW2sw = (short*)carve(16384 * 2);
  int*   cnt   = (int*)carve((size_t)NN * 4);
  int*   offs  = (int*)carve((size_t)NN * 4);
  int*   bsum  = (int*)carve(256 * 4);
  int*   perm  = (int*)carve((size_t)NE * 4);

  float* xout_f = (float*)d_out;        // N*128
  float* pout_f = xout_f + NN * 128;    // N*3

  k_prep_weights<<<1008, 256, 0, stream>>>(We1, We2, Wn1, Wn2, cW1, cW2,
                                           W1sw, W2sw, Wn1sw, Wn2sw, cW1sw, cW2sw);
  k_init_xb<<<25000, 256, 0, stream>>>(x, Anode);
  k_edge_pre<<<3125, 256, 0, stream>>>(pos, eattr, ei, eaPad, nd);

  // build row-sorted edge permutation (CSR order)
  hipMemsetAsync(cnt, 0, (size_t)NN * 4, stream);
  k_hist<<<3125, 256, 0, stream>>>(ei, cnt);
  k_scan_block<<<196, 256, 0, stream>>>(cnt, offs, bsum);
  k_scan_top<<<1, 256, 0, stream>>>(bsum);
  k_scan_add<<<196, 256, 0, stream>>>(offs, bsum);
  k_scatter<<<3125, 256, 0, stream>>>(ei, offs, perm);

  for (int l = 0; l < 2; ++l) {
    hipMemsetAsync(agg, 0, (size_t)NN * 128 * 4, stream);
    k_edge_gemm<0><<<6250, 256, 0, stream>>>(Anode, eaPad, ei, perm,
        W1sw + l * 36864, W2sw + l * 16384, be1 + l * 128, be2 + l * 128,
        Watt + l * 128, batt + l, (const float*)nullptr, agg);
    k_nodeprep<<<25000, 256, 0, stream>>>(agg, Anode);
    k_node_gemm<<<391, 256, 0, stream>>>(Anode,
        Wn1sw + l * 32768, Wn2sw + l * 16384, bn1 + l * 128, bn2 + l * 128,
        l == 0 ? x : xcur, l == 0 ? xcur : xout_f);
  }
  hipMemsetAsync(pagg, 0, (size_t)NN * 3 * 4, stream);
  k_edge_gemm<1><<<6250, 256, 0, stream>>>(Anode, eaPad, ei, perm,
      cW1sw, cW2sw, cb1, cb2, cW3, (const float*)nullptr, nd, pagg);
  k_pos_final<<<587, 256, 0, stream>>>(pos, mask, pagg, pout_f);
}

// Round 4
// 946.479 us; speedup vs baseline: 1.2898x; 1.1033x over previous
//
#include <hip/hip_runtime.h>
#include <hip/hip_bf16.h>
#include <stdint.h>

#define NN 50000
#define NE 800000
#define HH 128

typedef __bf16 bf16x8 __attribute__((ext_vector_type(8)));
typedef float  f32x4  __attribute__((ext_vector_type(4)));

__device__ __forceinline__ unsigned short f2bf(float f) {
  union { float f; uint32_t u; } v; v.f = f;
  uint32_t r = v.u + 0x7FFFu + ((v.u >> 16) & 1u);
  return (unsigned short)(r >> 16);
}
__device__ __forceinline__ uint32_t pack2bf(float a, float b) {
  return (uint32_t)f2bf(a) | ((uint32_t)f2bf(b) << 16);
}
__device__ __forceinline__ float silu_f(float x) { return x / (1.f + __expf(-x)); }
__device__ __forceinline__ float sigm_f(float x) { return 1.f / (1.f + __expf(-x)); }

typedef const __attribute__((address_space(1))) void gvoid_t;
typedef __attribute__((address_space(3))) void lvoid_t;
// async global->LDS, 16B per lane; dst must be wave-uniform (HW adds lane*16)
__device__ __forceinline__ void gll16(const void* g, void* l) {
  __builtin_amdgcn_global_load_lds((gvoid_t*)g, (lvoid_t*)l, 16, 0, 0);
}

// LDS tile blocks: [rows][32 k] bf16, 16B chunk c stored at c ^ ((row>>1)&3)
__device__ __forceinline__ bf16x8 frag_ld(const short* blk, int row, int q) {
  int c = q ^ ((row >> 1) & 3);
  return *(const bf16x8*)(blk + row * 32 + c * 8);
}

// ---------------- weight prep: transpose to [kk][n][32k] swizzled bf16 ----------------
__global__ void k_prep_weights(const float* We1, const float* We2, const float* Wn1,
                               const float* Wn2, const float* cW1, const float* cW2,
                               short* W1sw, short* W2sw, short* Wn1sw, short* Wn2sw,
                               short* cW1sw, short* cW2sw) {
  int idx = blockIdx.x * 256 + threadIdx.x;
  const float* s; short* d; int ks;
  if (idx < 36864)                    { s = We1;           d = W1sw;          ks = 265; }
  else if ((idx -= 36864) < 36864)    { s = We1 + 33920;   d = W1sw + 36864;  ks = 265; }
  else if ((idx -= 36864) < 16384)    { s = We2;           d = W2sw;          ks = 128; }
  else if ((idx -= 16384) < 16384)    { s = We2 + 16384;   d = W2sw + 16384;  ks = 128; }
  else if ((idx -= 16384) < 32768)    { s = Wn1;           d = Wn1sw;         ks = 256; }
  else if ((idx -= 32768) < 32768)    { s = Wn1 + 32768;   d = Wn1sw + 32768; ks = 256; }
  else if ((idx -= 32768) < 16384)    { s = Wn2;           d = Wn2sw;         ks = 128; }
  else if ((idx -= 16384) < 16384)    { s = Wn2 + 16384;   d = Wn2sw + 16384; ks = 128; }
  else if ((idx -= 16384) < 36864)    { s = cW1;           d = cW1sw;         ks = 265; }
  else if ((idx -= 36864) < 16384)    { s = cW2;           d = cW2sw;         ks = 128; }
  else return;
  int kk = idx >> 12;
  int rem = idx & 4095;
  int n = rem >> 5, kw = rem & 31;
  int cp = kw >> 3, j = kw & 7;
  int c = cp ^ ((n >> 1) & 3);
  int k = kk * 32 + c * 8 + j;
  float v = (k < ks) ? s[k * 128 + n] : 0.f;
  d[idx] = (short)f2bf(v);
}

// ---------------- small prep kernels ----------------
__global__ void k_init_xb(const float* __restrict__ x, short* __restrict__ Anode) {
  int i = blockIdx.x * 256 + threadIdx.x;
  if (i < NN * HH) Anode[(i >> 7) * 256 + (i & 127)] = (short)f2bf(x[i]);
}
__global__ void k_nodeprep(const float* __restrict__ agg, short* __restrict__ Anode) {
  int i = blockIdx.x * 256 + threadIdx.x;
  if (i < NN * HH) Anode[(i >> 7) * 256 + 128 + (i & 127)] = (short)f2bf(agg[i] * 0.01f);
}
__global__ void k_edge_pre(const float* __restrict__ pos, const float* __restrict__ eattr,
                           const int* __restrict__ ei, short* __restrict__ eaPad,
                           float* __restrict__ nd) {
  int e = blockIdx.x * 256 + threadIdx.x;
  if (e >= NE) return;
  int r = ei[e], c = ei[NE + e];
  float dx = pos[r * 3 + 0] - pos[c * 3 + 0];
  float dy = pos[r * 3 + 1] - pos[c * 3 + 1];
  float dz = pos[r * 3 + 2] - pos[c * 3 + 2];
  float d2 = dx * dx + dy * dy + dz * dz;
  float inv = 1.f / (sqrtf(d2) + 1.f);   // NC = 1.0
  nd[e * 3 + 0] = dx * inv;
  nd[e * 3 + 1] = dy * inv;
  nd[e * 3 + 2] = dz * inv;
  union { unsigned short s[32]; uint4 v[4]; } buf;
  buf.s[0] = f2bf(d2);
#pragma unroll
  for (int j = 0; j < 8; ++j) buf.s[1 + j] = f2bf(eattr[e * 8 + j]);
#pragma unroll
  for (int j = 9; j < 32; ++j) buf.s[j] = 0;
  uint4* dst = (uint4*)(eaPad + (size_t)e * 32);
#pragma unroll
  for (int j = 0; j < 4; ++j) dst[j] = buf.v[j];
}
__global__ void k_pos_final(const float* __restrict__ pos, const float* __restrict__ mask,
                            const float* __restrict__ pagg, float* __restrict__ out) {
  int i = blockIdx.x * 256 + threadIdx.x;
  if (i < NN * 3) out[i] = pos[i] + pagg[i] * 0.01f * mask[i / 3];
}

// ---------------- CSR sort of edges by destination row ----------------
__global__ void k_hist(const int* __restrict__ ei, int* __restrict__ cnt) {
  int e = blockIdx.x * 256 + threadIdx.x;
  if (e < NE) atomicAdd(&cnt[ei[e]], 1);
}
__global__ void k_scan_block(const int* __restrict__ cnt, int* __restrict__ offs,
                             int* __restrict__ bsum) {
  __shared__ int s[256];
  int i = blockIdx.x * 256 + threadIdx.x;
  int v = (i < NN) ? cnt[i] : 0;
  s[threadIdx.x] = v;
  __syncthreads();
#pragma unroll
  for (int d = 1; d < 256; d <<= 1) {
    int t = (threadIdx.x >= d) ? s[threadIdx.x - d] : 0;
    __syncthreads();
    s[threadIdx.x] += t;
    __syncthreads();
  }
  if (i < NN) offs[i] = s[threadIdx.x] - v;
  if (threadIdx.x == 255) bsum[blockIdx.x] = s[255];
}
__global__ void k_scan_top(int* __restrict__ bsum) {
  __shared__ int s[256];
  int v = (threadIdx.x < 196) ? bsum[threadIdx.x] : 0;
  s[threadIdx.x] = v;
  __syncthreads();
#pragma unroll
  for (int d = 1; d < 256; d <<= 1) {
    int t = (threadIdx.x >= d) ? s[threadIdx.x - d] : 0;
    __syncthreads();
    s[threadIdx.x] += t;
    __syncthreads();
  }
  if (threadIdx.x < 196) bsum[threadIdx.x] = s[threadIdx.x] - v;
}
__global__ void k_scan_add(int* __restrict__ offs, const int* __restrict__ bsum) {
  int i = blockIdx.x * 256 + threadIdx.x;
  if (i < NN) offs[i] += bsum[blockIdx.x];
}
__global__ void k_scatter(const int* __restrict__ ei, int* __restrict__ offs,
                          int* __restrict__ perm) {
  int e = blockIdx.x * 256 + threadIdx.x;
  if (e < NE) {
    int p = atomicAdd(&offs[ei[e]], 1);
    perm[p] = e;
  }
}

// ---------------- fused edge/coord MLP GEMM (edges presorted by row) ----------------
// 64-edge tiles, 4 waves: wave (wm,wn) computes edges wm*32..+31 x chans wn*64..+63.
// COORD=0: m=silu(silu(he@W1+b1)@W2+b2); att=sigm(m@wred+batt);
//          agg[run][chan] = S @ (m*att) via MFMA (S = 0/1 segment matrix), few atomics
// COORD=1: g=silu(silu(he@W1+b1)@W2+b2); phi=g@wred; run-start walkers sum nd*phi, few atomics
template <int COORD>
__global__ __launch_bounds__(256) void k_edge_gemm(
    const short* __restrict__ Anode, const short* __restrict__ eaPad,
    const int* __restrict__ ei, const int* __restrict__ perm,
    const short* __restrict__ W1l, const short* __restrict__ W2l,
    const float* __restrict__ b1, const float* __restrict__ b2,
    const float* __restrict__ wred, const float* __restrict__ batt,
    const float* __restrict__ nd, float* outAcc) {
  __shared__ __align__(16) short A2s[8192];  // GEMM2 A-tile 4x[64][32]; then M-tile 2x[128 chan][32 edge]
  __shared__ short As[2048];                 // [64 edges][32 k]
  __shared__ short Bs[4096];                 // [128 chans][32 k]
  __shared__ float redp[64][2];
  __shared__ float redv[64];
  __shared__ int srow[64];
  __shared__ int eorg[64];
  __shared__ __align__(8) unsigned char srunS[64];
  __shared__ int runrowS[64];
  __shared__ int cntS[1];

  const int tid = threadIdx.x;
  const int lane = tid & 63;
  const int w = tid >> 6;
  const int ln = lane & 15, q = lane >> 4;
  const int wm = w >> 1, wn = w & 1;
  const int tile = blockIdx.x;

  if (tid < 64) {
    int eo = perm[tile * 64 + tid];
    eorg[tid] = eo;
    srow[tid] = ei[eo];
  }
  __syncthreads();

  // ---- segmented-run scan over sorted rows (wave 0 only) ----
  bool is_start = (tid < 64) && (tid == 0 || srow[tid] != srow[tid - 1]);
  unsigned long long bmask = __ballot(is_start);
  if (tid == 0) cntS[0] = __popcll(bmask);
  if (tid < 64) {
    int run = __popcll(bmask & ((1ull << lane) - 1ull)) + (is_start ? 1 : 0) - 1;
    srunS[tid] = (unsigned char)run;
    if (is_start) runrowS[run] = srow[tid];
  }
  // (published by the K-loop's first __syncthreads; read only after GEMM2)

  // per-lane staging source (16 rows per wave, 1 gll16/iter)
  const int el = w * 16 + (lane >> 2);
  const int rowv = srow[el];
  const int colv = ei[NE + eorg[el]];
  const int eo2 = eorg[el];
  const int kch = (lane & 3) ^ ((el >> 1) & 3);

  f32x4 acc[2][4];
  const f32x4 zero4 = {0.f, 0.f, 0.f, 0.f};
#pragma unroll
  for (int mi = 0; mi < 2; ++mi)
#pragma unroll
    for (int ni = 0; ni < 4; ++ni) acc[mi][ni] = zero4;

  // -------- GEMM1: he[64x288] @ W1[288x128] --------
  for (int kk = 0; kk < 9; ++kk) {
    __syncthreads();
#pragma unroll
    for (int j = 0; j < 2; ++j)
      gll16(W1l + kk * 4096 + w * 1024 + j * 512 + lane * 8, Bs + w * 1024 + j * 512);
    {
      int k0 = kk * 32 + kch * 8;
      const short* src;
      if (kk < 4)      src = Anode + (size_t)rowv * 256 + k0;
      else if (kk < 8) src = Anode + (size_t)colv * 256 + (k0 - 128);
      else             src = eaPad + (size_t)eo2 * 32 + (k0 - 256);
      gll16(src, As + (w * 16) * 32);
    }
    __syncthreads();
    bf16x8 af[2], bfr[4];
#pragma unroll
    for (int i = 0; i < 2; ++i) af[i] = frag_ld(As, wm * 32 + i * 16 + ln, q);
#pragma unroll
    for (int i = 0; i < 4; ++i) bfr[i] = frag_ld(Bs, wn * 64 + i * 16 + ln, q);
#pragma unroll
    for (int mi = 0; mi < 2; ++mi)
#pragma unroll
      for (int ni = 0; ni < 4; ++ni)
        acc[mi][ni] = __builtin_amdgcn_mfma_f32_16x16x32_bf16(af[mi], bfr[ni], acc[mi][ni], 0, 0, 0);
  }

  // -------- epilogue1: silu(h1+b1) -> A2s (bf16, 4x[64][32] swizzled blocks) --------
  float b1v[4];
#pragma unroll
  for (int ni = 0; ni < 4; ++ni) b1v[ni] = b1[wn * 64 + ni * 16 + ln];
#pragma unroll
  for (int mi = 0; mi < 2; ++mi)
#pragma unroll
    for (int ni = 0; ni < 4; ++ni) {
      int chan = wn * 64 + ni * 16 + ln;
      int kkb = chan >> 5, c = (chan >> 3) & 3, jj = chan & 7;
#pragma unroll
      for (int r = 0; r < 4; ++r) {
        int m = wm * 32 + mi * 16 + q * 4 + r;
        float v = silu_f(acc[mi][ni][r] + b1v[ni]);
        A2s[kkb * 2048 + m * 32 + ((c ^ ((m >> 1) & 3)) * 8) + jj] = (short)f2bf(v);
      }
    }

  // -------- GEMM2: h1s[64x128] @ W2[128x128] --------
  f32x4 acc2[2][4];
#pragma unroll
  for (int mi = 0; mi < 2; ++mi)
#pragma unroll
    for (int ni = 0; ni < 4; ++ni) acc2[mi][ni] = zero4;
  for (int kk = 0; kk < 4; ++kk) {
    __syncthreads();   // also publishes A2s writes on first iter
#pragma unroll
    for (int j = 0; j < 2; ++j)
      gll16(W2l + kk * 4096 + w * 1024 + j * 512 + lane * 8, Bs + w * 1024 + j * 512);
    __syncthreads();
    bf16x8 af[2], bfr[4];
#pragma unroll
    for (int i = 0; i < 2; ++i) af[i] = frag_ld(A2s + kk * 2048, wm * 32 + i * 16 + ln, q);
#pragma unroll
    for (int i = 0; i < 4; ++i) bfr[i] = frag_ld(Bs, wn * 64 + i * 16 + ln, q);
#pragma unroll
    for (int mi = 0; mi < 2; ++mi)
#pragma unroll
      for (int ni = 0; ni < 4; ++ni)
        acc2[mi][ni] = __builtin_amdgcn_mfma_f32_16x16x32_bf16(af[mi], bfr[ni], acc2[mi][ni], 0, 0, 0);
  }

  // -------- epilogue2: silu + attention/phi dot --------
  float b2v[4], wv[4];
#pragma unroll
  for (int ni = 0; ni < 4; ++ni) {
    int chan = wn * 64 + ni * 16 + ln;
    b2v[ni] = b2[chan];
    wv[ni] = wred[chan];
  }
  float p[2][4];
#pragma unroll
  for (int mi = 0; mi < 2; ++mi)
#pragma unroll
    for (int r = 0; r < 4; ++r) p[mi][r] = 0.f;
#pragma unroll
  for (int mi = 0; mi < 2; ++mi)
#pragma unroll
    for (int ni = 0; ni < 4; ++ni)
#pragma unroll
      for (int r = 0; r < 4; ++r) {
        float v = silu_f(acc2[mi][ni][r] + b2v[ni]);
        acc2[mi][ni][r] = v;
        p[mi][r] += v * wv[ni];
      }
#pragma unroll
  for (int d = 1; d < 16; d <<= 1)
#pragma unroll
    for (int mi = 0; mi < 2; ++mi)
#pragma unroll
      for (int r = 0; r < 4; ++r) p[mi][r] += __shfl_xor(p[mi][r], d, 64);
  __syncthreads();   // all waves done reading A2s (GEMM2) before overwrite
  if (ln == 0) {
#pragma unroll
    for (int mi = 0; mi < 2; ++mi)
#pragma unroll
      for (int r = 0; r < 4; ++r) redp[wm * 32 + mi * 16 + q * 4 + r][wn] = p[mi][r];
  }
  __syncthreads();

  if (COORD == 0) {
    if (tid < 64) redv[tid] = sigm_f(redp[tid][0] + redp[tid][1] + batt[0]);
    __syncthreads();
    // M-tile 2x[128 chan][32 edge] swizzled blocks (B-operand layout for S-GEMM);
    // 4 consecutive edges per C-tile -> packed ds_write_b64
#pragma unroll
    for (int mi = 0; mi < 2; ++mi) {
      int e0 = wm * 32 + mi * 16 + q * 4;
      float a0 = redv[e0 + 0], a1 = redv[e0 + 1], a2 = redv[e0 + 2], a3 = redv[e0 + 3];
#pragma unroll
      for (int ni = 0; ni < 4; ++ni) {
        int chan = wn * 64 + ni * 16 + ln;
        uint2 pkd;
        pkd.x = pack2bf(acc2[mi][ni][0] * a0, acc2[mi][ni][1] * a1);
        pkd.y = pack2bf(acc2[mi][ni][2] * a2, acc2[mi][ni][3] * a3);
        int addr = wm * 4096 + chan * 32 + ((((e0 >> 3) & 3) ^ ((chan >> 1) & 3)) * 8) + (e0 & 7);
        *(uint2*)(A2s + addr) = pkd;
      }
    }
    __syncthreads();
    // segment-sum via MFMA: agg[run][chan] = S[run][edge] @ M[edge][chan]
    const int nruns = cntS[0];
    bf16x8 bfrg[2][2];
#pragma unroll
    for (int kk = 0; kk < 2; ++kk)
#pragma unroll
      for (int ni = 0; ni < 2; ++ni)
        bfrg[kk][ni] = frag_ld(A2s + kk * 4096, w * 32 + ni * 16 + ln, q);
    const int npass = (nruns + 15) >> 4;
    for (int pp = 0; pp < npass; ++pp) {
      const unsigned int base = pp * 16;
      f32x4 a3c[2] = {zero4, zero4};
#pragma unroll
      for (int kk = 0; kk < 2; ++kk) {
        uint2 sb = *(const uint2*)(srunS + kk * 32 + q * 8);
        union { short s[8]; bf16x8 v; } af;
#pragma unroll
        for (int j = 0; j < 4; ++j)
          af.s[j] = (((sb.x >> (8 * j)) & 255u) == base + (unsigned)ln) ? (short)0x3F80 : (short)0;
#pragma unroll
        for (int j = 0; j < 4; ++j)
          af.s[4 + j] = (((sb.y >> (8 * j)) & 255u) == base + (unsigned)ln) ? (short)0x3F80 : (short)0;
        a3c[0] = __builtin_amdgcn_mfma_f32_16x16x32_bf16(af.v, bfrg[kk][0], a3c[0], 0, 0, 0);
        a3c[1] = __builtin_amdgcn_mfma_f32_16x16x32_bf16(af.v, bfrg[kk][1], a3c[1], 0, 0, 0);
      }
#pragma unroll
      for (int ni = 0; ni < 2; ++ni)
#pragma unroll
        for (int r = 0; r < 4; ++r) {
          int run = (int)base + q * 4 + r;
          if (run < nruns) {
            int rw = runrowS[run];
            atomicAdd(&outAcc[(size_t)rw * 128 + (w * 32 + ni * 16 + ln)], a3c[ni][r]);
          }
        }
    }
  } else {
    float* ndl = (float*)A2s;   // reuse: [64][3]
    if (tid < 64) {
      int eo = eorg[tid];
      float phi = redp[tid][0] + redp[tid][1];
      ndl[tid * 3 + 0] = nd[eo * 3 + 0] * phi;
      ndl[tid * 3 + 1] = nd[eo * 3 + 1] * phi;
      ndl[tid * 3 + 2] = nd[eo * 3 + 2] * phi;
    }
    __syncthreads();
    if (is_start) {   // run-start walkers (tid<64 implied)
      int myrow = srow[tid];
      float s0 = 0.f, s1 = 0.f, s2 = 0.f;
      for (int j = tid; j < 64 && srow[j] == myrow; ++j) {
        s0 += ndl[j * 3 + 0];
        s1 += ndl[j * 3 + 1];
        s2 += ndl[j * 3 + 2];
      }
      atomicAdd(&outAcc[myrow * 3 + 0], s0);
      atomicAdd(&outAcc[myrow * 3 + 1], s1);
      atomicAdd(&outAcc[myrow * 3 + 2], s2);
    }
  }
}

// ---------------- node MLP GEMM (residual update, 128-node tiles) ----------------
__global__ __launch_bounds__(256) void k_node_gemm(
    short* Anode, const short* __restrict__ Wn1l, const short* __restrict__ Wn2l,
    const float* __restrict__ b1, const float* __restrict__ b2,
    const float* __restrict__ xres, float* __restrict__ xout) {
  __shared__ short A2s[4 * 4096];
  __shared__ short As[4096];
  __shared__ short Bs[4096];

  const int tid = threadIdx.x;
  const int lane = tid & 63;
  const int w = tid >> 6;
  const int ln = lane & 15, q = lane >> 4;
  const int wm = w >> 1, wn = w & 1;
  const int tile = blockIdx.x;

  int nl[2], nclamp[2], kch[2];
#pragma unroll
  for (int j = 0; j < 2; ++j) {
    nl[j] = w * 32 + j * 16 + (lane >> 2);
    int node = tile * 128 + nl[j];
    nclamp[j] = node < NN ? node : (NN - 1);
    kch[j] = (lane & 3) ^ ((nl[j] >> 1) & 3);
  }

  f32x4 acc[4][4];
  const f32x4 zero4 = {0.f, 0.f, 0.f, 0.f};
#pragma unroll
  for (int mi = 0; mi < 4; ++mi)
#pragma unroll
    for (int ni = 0; ni < 4; ++ni) acc[mi][ni] = zero4;

  for (int kk = 0; kk < 8; ++kk) {
    __syncthreads();
#pragma unroll
    for (int j = 0; j < 2; ++j)
      gll16(Wn1l + kk * 4096 + w * 1024 + j * 512 + lane * 8, Bs + w * 1024 + j * 512);
#pragma unroll
    for (int j = 0; j < 2; ++j)
      gll16(Anode + (size_t)nclamp[j] * 256 + kk * 32 + kch[j] * 8, As + (w * 32 + j * 16) * 32);
    __syncthreads();
    bf16x8 af[4], bfr[4];
#pragma unroll
    for (int i = 0; i < 4; ++i) af[i] = frag_ld(As, wm * 64 + i * 16 + ln, q);
#pragma unroll
    for (int i = 0; i < 4; ++i) bfr[i] = frag_ld(Bs, wn * 64 + i * 16 + ln, q);
#pragma unroll
    for (int mi = 0; mi < 4; ++mi)
#pragma unroll
      for (int ni = 0; ni < 4; ++ni)
        acc[mi][ni] = __builtin_amdgcn_mfma_f32_16x16x32_bf16(af[mi], bfr[ni], acc[mi][ni], 0, 0, 0);
  }

  float b1v[4];
#pragma unroll
  for (int ni = 0; ni < 4; ++ni) b1v[ni] = b1[wn * 64 + ni * 16 + ln];
#pragma unroll
  for (int mi = 0; mi < 4; ++mi)
#pragma unroll
    for (int ni = 0; ni < 4; ++ni) {
      int chan = wn * 64 + ni * 16 + ln;
      int kkb = chan >> 5, c = (chan >> 3) & 3, jj = chan & 7;
#pragma unroll
      for (int r = 0; r < 4; ++r) {
        int m = wm * 64 + mi * 16 + q * 4 + r;
        float v = silu_f(acc[mi][ni][r] + b1v[ni]);
        A2s[kkb * 4096 + m * 32 + ((c ^ ((m >> 1) & 3)) * 8) + jj] = (short)f2bf(v);
      }
    }

  f32x4 acc2[4][4];
#pragma unroll
  for (int mi = 0; mi < 4; ++mi)
#pragma unroll
    for (int ni = 0; ni < 4; ++ni) acc2[mi][ni] = zero4;
  for (int kk = 0; kk < 4; ++kk) {
    __syncthreads();
#pragma unroll
    for (int j = 0; j < 2; ++j)
      gll16(Wn2l + kk * 4096 + w * 1024 + j * 512 + lane * 8, Bs + w * 1024 + j * 512);
    __syncthreads();
    bf16x8 af[4], bfr[4];
#pragma unroll
    for (int i = 0; i < 4; ++i) af[i] = frag_ld(A2s + kk * 4096, wm * 64 + i * 16 + ln, q);
#pragma unroll
    for (int i = 0; i < 4; ++i) bfr[i] = frag_ld(Bs, wn * 64 + i * 16 + ln, q);
#pragma unroll
    for (int mi = 0; mi < 4; ++mi)
#pragma unroll
      for (int ni = 0; ni < 4; ++ni)
        acc2[mi][ni] = __builtin_amdgcn_mfma_f32_16x16x32_bf16(af[mi], bfr[ni], acc2[mi][ni], 0, 0, 0);
  }

  float b2v[4];
#pragma unroll
  for (int ni = 0; ni < 4; ++ni) b2v[ni] = b2[wn * 64 + ni * 16 + ln];
#pragma unroll
  for (int mi = 0; mi < 4; ++mi)
#pragma unroll
    for (int r = 0; r < 4; ++r) {
      int m = wm * 64 + mi * 16 + q * 4 + r;
      int node = tile * 128 + m;
      if (node < NN) {
#pragma unroll
        for (int ni = 0; ni < 4; ++ni) {
          int chan = wn * 64 + ni * 16 + ln;
          float v = acc2[mi][ni][r] + b2v[ni] + xres[(size_t)node * 128 + chan];
          xout[(size_t)node * 128 + chan] = v;
          Anode[(size_t)node * 256 + chan] = (short)f2bf(v);
        }
      }
    }
}

extern "C" void kernel_launch(void* const* d_in, const int* in_sizes, int n_in,
                              void* d_out, int out_size, void* d_ws, size_t ws_size,
                              hipStream_t stream) {
  const float* x    = (const float*)d_in[0];
  const float* pos  = (const float*)d_in[1];
  const float* mask = (const float*)d_in[2];
  const float* eattr= (const float*)d_in[3];
  const int*   ei   = (const int*)d_in[4];
  const float* We1  = (const float*)d_in[5];
  const float* be1  = (const float*)d_in[6];
  const float* We2  = (const float*)d_in[7];
  const float* be2  = (const float*)d_in[8];
  const float* Watt = (const float*)d_in[9];
  const float* batt = (const float*)d_in[10];
  const float* Wn1  = (const float*)d_in[11];
  const float* bn1  = (const float*)d_in[12];
  const float* Wn2  = (const float*)d_in[13];
  const float* bn2  = (const float*)d_in[14];
  const float* cW1  = (const float*)d_in[15];
  const float* cb1  = (const float*)d_in[16];
  const float* cW2  = (const float*)d_in[17];
  const float* cb2  = (const float*)d_in[18];
  const float* cW3  = (const float*)d_in[19];

  char* p = (char*)d_ws;
  auto carve = [&](size_t bytes) { char* r = p; p += (bytes + 511) & ~(size_t)511; return r; };
  short* Anode = (short*)carve((size_t)NN * 256 * 2);
  short* eaPad = (short*)carve((size_t)NE * 32 * 2);
  float* nd    = (float*)carve((size_t)NE * 3 * 4);
  float* agg   = (float*)carve((size_t)NN * 128 * 4);
  float* xcur  = (float*)carve((size_t)NN * 128 * 4);
  float* pagg  = (float*)carve((size_t)NN * 3 * 4);
  short* W1sw  = (short*)carve(2 * 36864 * 2);
  short* W2sw  = (short*)carve(2 * 16384 * 2);
  short* Wn1sw = (short*)carve(2 * 32768 * 2);
  short* Wn2sw = (short*)carve(2 * 16384 * 2);
  short* cW1sw = (short*)carve(36864 * 2);
  short* cW2sw = (short*)carve(16384 * 2);
  int*   cnt   = (int*)carve((size_t)NN * 4);
  int*   offs  = (int*)carve((size_t)NN * 4);
  int*   bsum  = (int*)carve(256 * 4);
  int*   perm  = (int*)carve((size_t)NE * 4);

  float* xout_f = (float*)d_out;        // N*128
  float* pout_f = xout_f + NN * 128;    // N*3

  k_prep_weights<<<1008, 256, 0, stream>>>(We1, We2, Wn1, Wn2, cW1, cW2,
                                           W1sw, W2sw, Wn1sw, Wn2sw, cW1sw, cW2sw);
  k_init_xb<<<25000, 256, 0, stream>>>(x, Anode);
  k_edge_pre<<<3125, 256, 0, stream>>>(pos, eattr, ei, eaPad, nd);

  // build row-sorted edge permutation (CSR order)
  hipMemsetAsync(cnt, 0, (size_t)NN * 4, stream);
  k_hist<<<3125, 256, 0, stream>>>(ei, cnt);
  k_scan_block<<<196, 256, 0, stream>>>(cnt, offs, bsum);
  k_scan_top<<<1, 256, 0, stream>>>(bsum);
  k_scan_add<<<196, 256, 0, stream>>>(offs, bsum);
  k_scatter<<<3125, 256, 0, stream>>>(ei, offs, perm);

  for (int l = 0; l < 2; ++l) {
    hipMemsetAsync(agg, 0, (size_t)NN * 128 * 4, stream);
    k_edge_gemm<0><<<12500, 256, 0, stream>>>(Anode, eaPad, ei, perm,
        W1sw + l * 36864, W2sw + l * 16384, be1 + l * 128, be2 + l * 128,
        Watt + l * 128, batt + l, (const float*)nullptr, agg);
    k_nodeprep<<<25000, 256, 0, stream>>>(agg, Anode);
    k_node_gemm<<<391, 256, 0, stream>>>(Anode,
        Wn1sw + l * 32768, Wn2sw + l * 16384, bn1 + l * 128, bn2 + l * 128,
        l == 0 ? x : xcur, l == 0 ? xcur : xout_f);
  }
  hipMemsetAsync(pagg, 0, (size_t)NN * 3 * 4, stream);
  k_edge_gemm<1><<<12500, 256, 0, stream>>>(Anode, eaPad, ei, perm,
      cW1sw, cW2sw, cb1, cb2, cW3, (const float*)nullptr, nd, pagg);
  k_pos_final<<<587, 256, 0, stream>>>(pos, mask, pagg, pout_f);
}

// Round 5
// 916.445 us; speedup vs baseline: 1.3321x; 1.0328x over previous
//
#include <hip/hip_runtime.h>
#include <hip/hip_bf16.h>
#include <stdint.h>

#define NN 50000
#define NE 800000
#define HH 128

typedef __bf16 bf16x8 __attribute__((ext_vector_type(8)));
typedef float  f32x4  __attribute__((ext_vector_type(4)));

__device__ __forceinline__ unsigned short f2bf(float f) {
  union { float f; uint32_t u; } v; v.f = f;
  uint32_t r = v.u + 0x7FFFu + ((v.u >> 16) & 1u);
  return (unsigned short)(r >> 16);
}
#if __has_builtin(__builtin_amdgcn_cvt_pk_bf16_f32)
typedef __bf16 bf16x2 __attribute__((ext_vector_type(2)));
__device__ __forceinline__ uint32_t pack2bf(float a, float b) {
  union { bf16x2 v; uint32_t u; } t;
  t.v = __builtin_amdgcn_cvt_pk_bf16_f32(a, b);
  return t.u;
}
#else
__device__ __forceinline__ uint32_t pack2bf(float a, float b) {
  return (uint32_t)f2bf(a) | ((uint32_t)f2bf(b) << 16);
}
#endif
// fast silu/sigmoid: v_rcp instead of IEEE division sequence (bf16 output, 1ulp is fine)
__device__ __forceinline__ float silu_f(float x) {
  return x * __builtin_amdgcn_rcpf(1.f + __expf(-x));
}
__device__ __forceinline__ float sigm_f(float x) {
  return __builtin_amdgcn_rcpf(1.f + __expf(-x));
}

typedef const __attribute__((address_space(1))) void gvoid_t;
typedef __attribute__((address_space(3))) void lvoid_t;
// async global->LDS, 16B per lane; dst must be wave-uniform (HW adds lane*16)
__device__ __forceinline__ void gll16(const void* g, void* l) {
  __builtin_amdgcn_global_load_lds((gvoid_t*)g, (lvoid_t*)l, 16, 0, 0);
}

// LDS tile blocks: [rows][32 k] bf16, 16B chunk c stored at c ^ ((row>>1)&3)
__device__ __forceinline__ bf16x8 frag_ld(const short* blk, int row, int q) {
  int c = q ^ ((row >> 1) & 3);
  return *(const bf16x8*)(blk + row * 32 + c * 8);
}

// ---------------- weight prep: transpose to [kk][n][32k] swizzled bf16 ----------------
__global__ void k_prep_weights(const float* We1, const float* We2, const float* Wn1,
                               const float* Wn2, const float* cW1, const float* cW2,
                               short* W1sw, short* W2sw, short* Wn1sw, short* Wn2sw,
                               short* cW1sw, short* cW2sw) {
  int idx = blockIdx.x * 256 + threadIdx.x;
  const float* s; short* d; int ks;
  if (idx < 36864)                    { s = We1;           d = W1sw;          ks = 265; }
  else if ((idx -= 36864) < 36864)    { s = We1 + 33920;   d = W1sw + 36864;  ks = 265; }
  else if ((idx -= 36864) < 16384)    { s = We2;           d = W2sw;          ks = 128; }
  else if ((idx -= 16384) < 16384)    { s = We2 + 16384;   d = W2sw + 16384;  ks = 128; }
  else if ((idx -= 16384) < 32768)    { s = Wn1;           d = Wn1sw;         ks = 256; }
  else if ((idx -= 32768) < 32768)    { s = Wn1 + 32768;   d = Wn1sw + 32768; ks = 256; }
  else if ((idx -= 32768) < 16384)    { s = Wn2;           d = Wn2sw;         ks = 128; }
  else if ((idx -= 16384) < 16384)    { s = Wn2 + 16384;   d = Wn2sw + 16384; ks = 128; }
  else if ((idx -= 16384) < 36864)    { s = cW1;           d = cW1sw;         ks = 265; }
  else if ((idx -= 36864) < 16384)    { s = cW2;           d = cW2sw;         ks = 128; }
  else return;
  int kk = idx >> 12;
  int rem = idx & 4095;
  int n = rem >> 5, kw = rem & 31;
  int cp = kw >> 3, j = kw & 7;
  int c = cp ^ ((n >> 1) & 3);
  int k = kk * 32 + c * 8 + j;
  float v = (k < ks) ? s[k * 128 + n] : 0.f;
  d[idx] = (short)f2bf(v);
}

// ---------------- small prep kernels ----------------
__global__ void k_init_xb(const float* __restrict__ x, short* __restrict__ Anode) {
  int i = blockIdx.x * 256 + threadIdx.x;
  if (i < NN * HH) Anode[(i >> 7) * 256 + (i & 127)] = (short)f2bf(x[i]);
}
__global__ void k_nodeprep(const float* __restrict__ agg, short* __restrict__ Anode) {
  int i = blockIdx.x * 256 + threadIdx.x;
  if (i < NN * HH) Anode[(i >> 7) * 256 + 128 + (i & 127)] = (short)f2bf(agg[i] * 0.01f);
}
__global__ void k_edge_pre(const float* __restrict__ pos, const float* __restrict__ eattr,
                           const int* __restrict__ ei, short* __restrict__ eaPad,
                           float* __restrict__ nd) {
  int e = blockIdx.x * 256 + threadIdx.x;
  if (e >= NE) return;
  int r = ei[e], c = ei[NE + e];
  float dx = pos[r * 3 + 0] - pos[c * 3 + 0];
  float dy = pos[r * 3 + 1] - pos[c * 3 + 1];
  float dz = pos[r * 3 + 2] - pos[c * 3 + 2];
  float d2 = dx * dx + dy * dy + dz * dz;
  float inv = __builtin_amdgcn_rcpf(sqrtf(d2) + 1.f);   // NC = 1.0
  nd[e * 3 + 0] = dx * inv;
  nd[e * 3 + 1] = dy * inv;
  nd[e * 3 + 2] = dz * inv;
  union { unsigned short s[32]; uint4 v[4]; } buf;
  buf.s[0] = f2bf(d2);
#pragma unroll
  for (int j = 0; j < 8; ++j) buf.s[1 + j] = f2bf(eattr[e * 8 + j]);
#pragma unroll
  for (int j = 9; j < 32; ++j) buf.s[j] = 0;
  uint4* dst = (uint4*)(eaPad + (size_t)e * 32);
#pragma unroll
  for (int j = 0; j < 4; ++j) dst[j] = buf.v[j];
}
__global__ void k_pos_final(const float* __restrict__ pos, const float* __restrict__ mask,
                            const float* __restrict__ pagg, float* __restrict__ out) {
  int i = blockIdx.x * 256 + threadIdx.x;
  if (i < NN * 3) out[i] = pos[i] + pagg[i] * 0.01f * mask[i / 3];
}

// ---------------- CSR sort of edges by destination row ----------------
__global__ void k_hist(const int* __restrict__ ei, int* __restrict__ cnt) {
  int e = blockIdx.x * 256 + threadIdx.x;
  if (e < NE) atomicAdd(&cnt[ei[e]], 1);
}
__global__ void k_scan_block(const int* __restrict__ cnt, int* __restrict__ offs,
                             int* __restrict__ bsum) {
  __shared__ int s[256];
  int i = blockIdx.x * 256 + threadIdx.x;
  int v = (i < NN) ? cnt[i] : 0;
  s[threadIdx.x] = v;
  __syncthreads();
#pragma unroll
  for (int d = 1; d < 256; d <<= 1) {
    int t = (threadIdx.x >= d) ? s[threadIdx.x - d] : 0;
    __syncthreads();
    s[threadIdx.x] += t;
    __syncthreads();
  }
  if (i < NN) offs[i] = s[threadIdx.x] - v;
  if (threadIdx.x == 255) bsum[blockIdx.x] = s[255];
}
__global__ void k_scan_top(int* __restrict__ bsum) {
  __shared__ int s[256];
  int v = (threadIdx.x < 196) ? bsum[threadIdx.x] : 0;
  s[threadIdx.x] = v;
  __syncthreads();
#pragma unroll
  for (int d = 1; d < 256; d <<= 1) {
    int t = (threadIdx.x >= d) ? s[threadIdx.x - d] : 0;
    __syncthreads();
    s[threadIdx.x] += t;
    __syncthreads();
  }
  if (threadIdx.x < 196) bsum[threadIdx.x] = s[threadIdx.x] - v;
}
__global__ void k_scan_add(int* __restrict__ offs, const int* __restrict__ bsum) {
  int i = blockIdx.x * 256 + threadIdx.x;
  if (i < NN) offs[i] += bsum[blockIdx.x];
}
__global__ void k_scatter(const int* __restrict__ ei, int* __restrict__ offs,
                          int* __restrict__ perm) {
  int e = blockIdx.x * 256 + threadIdx.x;
  if (e < NE) {
    int p = atomicAdd(&offs[ei[e]], 1);
    perm[p] = e;
  }
}

// ---------------- fused edge/coord MLP GEMM (edges presorted by row) ----------------
// TRANSPOSED MFMA: A=W-frag, B=he-frag => D[chan][edge] (lane=edge). This makes the
// h1 LDS round-trip a packed ds_write_b64 and the attention dot mostly in-lane.
// 64-edge tiles, 4 waves: wave (wm,wn): chans wn*64..+63 (rows) x edges wm*32..+31 (cols).
template <int COORD>
__global__ __launch_bounds__(256) void k_edge_gemm(
    const short* __restrict__ Anode, const short* __restrict__ eaPad,
    const int* __restrict__ ei, const int* __restrict__ perm,
    const short* __restrict__ W1l, const short* __restrict__ W2l,
    const float* __restrict__ b1, const float* __restrict__ b2,
    const float* __restrict__ wred, const float* __restrict__ batt,
    const float* __restrict__ nd, float* outAcc) {
  __shared__ __align__(16) short A2s[8192];  // h1^T 4x[64e][32c]; then M 2x[128c][32e]
  __shared__ short As[2048];                 // [64 edges][32 k]
  __shared__ short Bs[4096];                 // [128 chans][32 k]
  __shared__ float redp[64][2];
  __shared__ float redv[64];
  __shared__ int srow[64];
  __shared__ int eorg[64];
  __shared__ __align__(8) unsigned char srunS[64];
  __shared__ int runrowS[64];
  __shared__ int cntS[1];

  const int tid = threadIdx.x;
  const int lane = tid & 63;
  const int w = tid >> 6;
  const int ln = lane & 15, q = lane >> 4;
  const int wm = w >> 1, wn = w & 1;
  const int tile = blockIdx.x;

  if (tid < 64) {
    int eo = perm[tile * 64 + tid];
    eorg[tid] = eo;
    srow[tid] = ei[eo];
  }
  __syncthreads();

  // ---- segmented-run scan over sorted rows (wave 0 only) ----
  bool is_start = (tid < 64) && (tid == 0 || srow[tid] != srow[tid - 1]);
  unsigned long long bmask = __ballot(is_start);
  if (tid == 0) cntS[0] = __popcll(bmask);
  if (tid < 64) {
    int run = __popcll(bmask & ((1ull << lane) - 1ull)) + (is_start ? 1 : 0) - 1;
    srunS[tid] = (unsigned char)run;
    if (is_start) runrowS[run] = srow[tid];
  }
  // (published by the K-loop's first __syncthreads; read only after GEMM2)

  // per-lane staging source (16 rows per wave, 1 gll16/iter)
  const int el = w * 16 + (lane >> 2);
  const int rowv = srow[el];
  const int colv = ei[NE + eorg[el]];
  const int eo2 = eorg[el];
  const int kch = (lane & 3) ^ ((el >> 1) & 3);

  f32x4 acc[4][2];                           // [chan-tile ni][edge-tile mi]
  const f32x4 zero4 = {0.f, 0.f, 0.f, 0.f};
#pragma unroll
  for (int ni = 0; ni < 4; ++ni)
#pragma unroll
    for (int mi = 0; mi < 2; ++mi) acc[ni][mi] = zero4;

  // -------- GEMM1: h1^T[128c x 64e] = W1^T(A) x he^T(B) --------
  for (int kk = 0; kk < 9; ++kk) {
    __syncthreads();
#pragma unroll
    for (int j = 0; j < 2; ++j)
      gll16(W1l + kk * 4096 + w * 1024 + j * 512 + lane * 8, Bs + w * 1024 + j * 512);
    {
      int k0 = kk * 32 + kch * 8;
      const short* src;
      if (kk < 4)      src = Anode + (size_t)rowv * 256 + k0;
      else if (kk < 8) src = Anode + (size_t)colv * 256 + (k0 - 128);
      else             src = eaPad + (size_t)eo2 * 32 + (k0 - 256);
      gll16(src, As + (w * 16) * 32);
    }
    __syncthreads();
    bf16x8 wf[4], hf[2];
#pragma unroll
    for (int i = 0; i < 4; ++i) wf[i] = frag_ld(Bs, wn * 64 + i * 16 + ln, q);
#pragma unroll
    for (int i = 0; i < 2; ++i) hf[i] = frag_ld(As, wm * 32 + i * 16 + ln, q);
#pragma unroll
    for (int ni = 0; ni < 4; ++ni)
#pragma unroll
      for (int mi = 0; mi < 2; ++mi)
        acc[ni][mi] = __builtin_amdgcn_mfma_f32_16x16x32_bf16(wf[ni], hf[mi], acc[ni][mi], 0, 0, 0);
  }

  // -------- epilogue1: silu(h1+b1) -> A2s [edge][chan] via packed b64 writes --------
  float4 b1v[4];
#pragma unroll
  for (int ni = 0; ni < 4; ++ni)
    b1v[ni] = *(const float4*)(b1 + wn * 64 + ni * 16 + q * 4);
#pragma unroll
  for (int ni = 0; ni < 4; ++ni) {
    int cb = wn * 64 + ni * 16 + q * 4;            // 4 consecutive chans per lane
    int kkb = cb >> 5, cc = (cb >> 3) & 3, j0 = cb & 7;
#pragma unroll
    for (int mi = 0; mi < 2; ++mi) {
      int edge = wm * 32 + mi * 16 + ln;
      int addr = kkb * 2048 + edge * 32 + ((cc ^ ((edge >> 1) & 3)) * 8) + j0;
      uint2 pk;
      pk.x = pack2bf(silu_f(acc[ni][mi][0] + b1v[ni].x), silu_f(acc[ni][mi][1] + b1v[ni].y));
      pk.y = pack2bf(silu_f(acc[ni][mi][2] + b1v[ni].z), silu_f(acc[ni][mi][3] + b1v[ni].w));
      *(uint2*)(A2s + addr) = pk;
    }
  }

  // -------- GEMM2: M^T[128c2 x 64e] = W2^T(A) x h1^T(B) --------
  f32x4 acc2[4][2];
#pragma unroll
  for (int ni = 0; ni < 4; ++ni)
#pragma unroll
    for (int mi = 0; mi < 2; ++mi) acc2[ni][mi] = zero4;
  for (int kk = 0; kk < 4; ++kk) {
    __syncthreads();   // also publishes A2s writes on first iter
#pragma unroll
    for (int j = 0; j < 2; ++j)
      gll16(W2l + kk * 4096 + w * 1024 + j * 512 + lane * 8, Bs + w * 1024 + j * 512);
    __syncthreads();
    bf16x8 wf[4], hf[2];
#pragma unroll
    for (int i = 0; i < 4; ++i) wf[i] = frag_ld(Bs, wn * 64 + i * 16 + ln, q);
#pragma unroll
    for (int i = 0; i < 2; ++i) hf[i] = frag_ld(A2s + kk * 2048, wm * 32 + i * 16 + ln, q);
#pragma unroll
    for (int ni = 0; ni < 4; ++ni)
#pragma unroll
      for (int mi = 0; mi < 2; ++mi)
        acc2[ni][mi] = __builtin_amdgcn_mfma_f32_16x16x32_bf16(wf[ni], hf[mi], acc2[ni][mi], 0, 0, 0);
  }

  // -------- epilogue2: silu + attention/phi dot (mostly in-lane) --------
  float4 b2v[4], wv[4];
#pragma unroll
  for (int ni = 0; ni < 4; ++ni) {
    b2v[ni] = *(const float4*)(b2 + wn * 64 + ni * 16 + q * 4);
    wv[ni]  = *(const float4*)(wred + wn * 64 + ni * 16 + q * 4);
  }
  float p[2] = {0.f, 0.f};
#pragma unroll
  for (int ni = 0; ni < 4; ++ni)
#pragma unroll
    for (int mi = 0; mi < 2; ++mi)
#pragma unroll
      for (int r = 0; r < 4; ++r) {
        float v = silu_f(acc2[ni][mi][r] + ((const float*)&b2v[ni])[r]);
        acc2[ni][mi][r] = v;
        p[mi] += v * ((const float*)&wv[ni])[r];
      }
#pragma unroll
  for (int mi = 0; mi < 2; ++mi) {
    p[mi] += __shfl_xor(p[mi], 16, 64);
    p[mi] += __shfl_xor(p[mi], 32, 64);
  }
  if (lane < 16) {
#pragma unroll
    for (int mi = 0; mi < 2; ++mi) redp[wm * 32 + mi * 16 + ln][wn] = p[mi];
  }
  __syncthreads();   // redp ready; all waves done with A2s (GEMM2)

  if (COORD == 0) {
    if (tid < 64) redv[tid] = sigm_f(redp[tid][0] + redp[tid][1] + batt[0]);
    __syncthreads();
    // M-tile 2x[128 chan][32 edge] swizzled blocks (B-operand layout for S-GEMM)
    float attv[2] = {redv[wm * 32 + ln], redv[wm * 32 + 16 + ln]};
#pragma unroll
    for (int ni = 0; ni < 4; ++ni)
#pragma unroll
      for (int mi = 0; mi < 2; ++mi) {
        int eb = mi * 16 + ln;
        int cE = (eb >> 3) & 3, jE = eb & 7;
#pragma unroll
        for (int r = 0; r < 4; ++r) {
          int chan2 = wn * 64 + ni * 16 + q * 4 + r;
          int addr = wm * 4096 + chan2 * 32 + ((cE ^ ((chan2 >> 1) & 3)) * 8) + jE;
          union { float f; uint32_t u; } vv;
          vv.f = acc2[ni][mi][r] * attv[mi];
          A2s[addr] = (short)((vv.u + 0x8000u) >> 16);   // round-half-up to bf16
        }
      }
    __syncthreads();
    // segment-sum via MFMA: agg[run][chan] = S[run][edge] @ M[edge][chan]
    const int nruns = cntS[0];
    bf16x8 bfrg[2][2];
#pragma unroll
    for (int kk = 0; kk < 2; ++kk)
#pragma unroll
      for (int ni = 0; ni < 2; ++ni)
        bfrg[kk][ni] = frag_ld(A2s + kk * 4096, w * 32 + ni * 16 + ln, q);
    const int npass = (nruns + 15) >> 4;
    for (int pp = 0; pp < npass; ++pp) {
      const unsigned int base = pp * 16;
      f32x4 a3c[2] = {zero4, zero4};
#pragma unroll
      for (int kk = 0; kk < 2; ++kk) {
        uint2 sb = *(const uint2*)(srunS + kk * 32 + q * 8);
        union { short s[8]; bf16x8 v; } af;
#pragma unroll
        for (int j = 0; j < 4; ++j)
          af.s[j] = (((sb.x >> (8 * j)) & 255u) == base + (unsigned)ln) ? (short)0x3F80 : (short)0;
#pragma unroll
        for (int j = 0; j < 4; ++j)
          af.s[4 + j] = (((sb.y >> (8 * j)) & 255u) == base + (unsigned)ln) ? (short)0x3F80 : (short)0;
        a3c[0] = __builtin_amdgcn_mfma_f32_16x16x32_bf16(af.v, bfrg[kk][0], a3c[0], 0, 0, 0);
        a3c[1] = __builtin_amdgcn_mfma_f32_16x16x32_bf16(af.v, bfrg[kk][1], a3c[1], 0, 0, 0);
      }
#pragma unroll
      for (int ni = 0; ni < 2; ++ni)
#pragma unroll
        for (int r = 0; r < 4; ++r) {
          int run = (int)base + q * 4 + r;
          if (run < nruns) {
            int rw = runrowS[run];
            atomicAdd(&outAcc[(size_t)rw * 128 + (w * 32 + ni * 16 + ln)], a3c[ni][r]);
          }
        }
    }
  } else {
    float* ndl = (float*)A2s;   // reuse: [64][3]
    if (tid < 64) {
      int eo = eorg[tid];
      float phi = redp[tid][0] + redp[tid][1];
      ndl[tid * 3 + 0] = nd[eo * 3 + 0] * phi;
      ndl[tid * 3 + 1] = nd[eo * 3 + 1] * phi;
      ndl[tid * 3 + 2] = nd[eo * 3 + 2] * phi;
    }
    __syncthreads();
    if (is_start) {   // run-start walkers (tid<64 implied)
      int myrow = srow[tid];
      float s0 = 0.f, s1 = 0.f, s2 = 0.f;
      for (int j = tid; j < 64 && srow[j] == myrow; ++j) {
        s0 += ndl[j * 3 + 0];
        s1 += ndl[j * 3 + 1];
        s2 += ndl[j * 3 + 2];
      }
      atomicAdd(&outAcc[myrow * 3 + 0], s0);
      atomicAdd(&outAcc[myrow * 3 + 1], s1);
      atomicAdd(&outAcc[myrow * 3 + 2], s2);
    }
  }
}

// ---------------- node MLP GEMM (residual update, 128-node tiles) ----------------
__global__ __launch_bounds__(256) void k_node_gemm(
    short* Anode, const short* __restrict__ Wn1l, const short* __restrict__ Wn2l,
    const float* __restrict__ b1, const float* __restrict__ b2,
    const float* __restrict__ xres, float* __restrict__ xout) {
  __shared__ short A2s[4 * 4096];
  __shared__ short As[4096];
  __shared__ short Bs[4096];

  const int tid = threadIdx.x;
  const int lane = tid & 63;
  const int w = tid >> 6;
  const int ln = lane & 15, q = lane >> 4;
  const int wm = w >> 1, wn = w & 1;
  const int tile = blockIdx.x;

  int nl[2], nclamp[2], kch[2];
#pragma unroll
  for (int j = 0; j < 2; ++j) {
    nl[j] = w * 32 + j * 16 + (lane >> 2);
    int node = tile * 128 + nl[j];
    nclamp[j] = node < NN ? node : (NN - 1);
    kch[j] = (lane & 3) ^ ((nl[j] >> 1) & 3);
  }

  f32x4 acc[4][4];
  const f32x4 zero4 = {0.f, 0.f, 0.f, 0.f};
#pragma unroll
  for (int mi = 0; mi < 4; ++mi)
#pragma unroll
    for (int ni = 0; ni < 4; ++ni) acc[mi][ni] = zero4;

  for (int kk = 0; kk < 8; ++kk) {
    __syncthreads();
#pragma unroll
    for (int j = 0; j < 2; ++j)
      gll16(Wn1l + kk * 4096 + w * 1024 + j * 512 + lane * 8, Bs + w * 1024 + j * 512);
#pragma unroll
    for (int j = 0; j < 2; ++j)
      gll16(Anode + (size_t)nclamp[j] * 256 + kk * 32 + kch[j] * 8, As + (w * 32 + j * 16) * 32);
    __syncthreads();
    bf16x8 af[4], bfr[4];
#pragma unroll
    for (int i = 0; i < 4; ++i) af[i] = frag_ld(As, wm * 64 + i * 16 + ln, q);
#pragma unroll
    for (int i = 0; i < 4; ++i) bfr[i] = frag_ld(Bs, wn * 64 + i * 16 + ln, q);
#pragma unroll
    for (int mi = 0; mi < 4; ++mi)
#pragma unroll
      for (int ni = 0; ni < 4; ++ni)
        acc[mi][ni] = __builtin_amdgcn_mfma_f32_16x16x32_bf16(af[mi], bfr[ni], acc[mi][ni], 0, 0, 0);
  }

  float b1v[4];
#pragma unroll
  for (int ni = 0; ni < 4; ++ni) b1v[ni] = b1[wn * 64 + ni * 16 + ln];
#pragma unroll
  for (int mi = 0; mi < 4; ++mi)
#pragma unroll
    for (int ni = 0; ni < 4; ++ni) {
      int chan = wn * 64 + ni * 16 + ln;
      int kkb = chan >> 5, c = (chan >> 3) & 3, jj = chan & 7;
#pragma unroll
      for (int r = 0; r < 4; ++r) {
        int m = wm * 64 + mi * 16 + q * 4 + r;
        float v = silu_f(acc[mi][ni][r] + b1v[ni]);
        A2s[kkb * 4096 + m * 32 + ((c ^ ((m >> 1) & 3)) * 8) + jj] = (short)f2bf(v);
      }
    }

  f32x4 acc2[4][4];
#pragma unroll
  for (int mi = 0; mi < 4; ++mi)
#pragma unroll
    for (int ni = 0; ni < 4; ++ni) acc2[mi][ni] = zero4;
  for (int kk = 0; kk < 4; ++kk) {
    __syncthreads();
#pragma unroll
    for (int j = 0; j < 2; ++j)
      gll16(Wn2l + kk * 4096 + w * 1024 + j * 512 + lane * 8, Bs + w * 1024 + j * 512);
    __syncthreads();
    bf16x8 af[4], bfr[4];
#pragma unroll
    for (int i = 0; i < 4; ++i) af[i] = frag_ld(A2s + kk * 4096, wm * 64 + i * 16 + ln, q);
#pragma unroll
    for (int i = 0; i < 4; ++i) bfr[i] = frag_ld(Bs, wn * 64 + i * 16 + ln, q);
#pragma unroll
    for (int mi = 0; mi < 4; ++mi)
#pragma unroll
      for (int ni = 0; ni < 4; ++ni)
        acc2[mi][ni] = __builtin_amdgcn_mfma_f32_16x16x32_bf16(af[mi], bfr[ni], acc2[mi][ni], 0, 0, 0);
  }

  float b2v[4];
#pragma unroll
  for (int ni = 0; ni < 4; ++ni) b2v[ni] = b2[wn * 64 + ni * 16 + ln];
#pragma unroll
  for (int mi = 0; mi < 4; ++mi)
#pragma unroll
    for (int r = 0; r < 4; ++r) {
      int m = wm * 64 + mi * 16 + q * 4 + r;
      int node = tile * 128 + m;
      if (node < NN) {
#pragma unroll
        for (int ni = 0; ni < 4; ++ni) {
          int chan = wn * 64 + ni * 16 + ln;
          float v = acc2[mi][ni][r] + b2v[ni] + xres[(size_t)node * 128 + chan];
          xout[(size_t)node * 128 + chan] = v;
          Anode[(size_t)node * 256 + chan] = (short)f2bf(v);
        }
      }
    }
}

extern "C" void kernel_launch(void* const* d_in, const int* in_sizes, int n_in,
                              void* d_out, int out_size, void* d_ws, size_t ws_size,
                              hipStream_t stream) {
  const float* x    = (const float*)d_in[0];
  const float* pos  = (const float*)d_in[1];
  const float* mask = (const float*)d_in[2];
  const float* eattr= (const float*)d_in[3];
  const int*   ei   = (const int*)d_in[4];
  const float* We1  = (const float*)d_in[5];
  const float* be1  = (const float*)d_in[6];
  const float* We2  = (const float*)d_in[7];
  const float* be2  = (const float*)d_in[8];
  const float* Watt = (const float*)d_in[9];
  const float* batt = (const float*)d_in[10];
  const float* Wn1  = (const float*)d_in[11];
  const float* bn1  = (const float*)d_in[12];
  const float* Wn2  = (const float*)d_in[13];
  const float* bn2  = (const float*)d_in[14];
  const float* cW1  = (const float*)d_in[15];
  const float* cb1  = (const float*)d_in[16];
  const float* cW2  = (const float*)d_in[17];
  const float* cb2  = (const float*)d_in[18];
  const float* cW3  = (const float*)d_in[19];

  char* p = (char*)d_ws;
  auto carve = [&](size_t bytes) { char* r = p; p += (bytes + 511) & ~(size_t)511; return r; };
  short* Anode = (short*)carve((size_t)NN * 256 * 2);
  short* eaPad = (short*)carve((size_t)NE * 32 * 2);
  float* nd    = (float*)carve((size_t)NE * 3 * 4);
  float* agg   = (float*)carve((size_t)NN * 128 * 4);
  float* xcur  = (float*)carve((size_t)NN * 128 * 4);
  float* pagg  = (float*)carve((size_t)NN * 3 * 4);
  short* W1sw  = (short*)carve(2 * 36864 * 2);
  short* W2sw  = (short*)carve(2 * 16384 * 2);
  short* Wn1sw = (short*)carve(2 * 32768 * 2);
  short* Wn2sw = (short*)carve(2 * 16384 * 2);
  short* cW1sw = (short*)carve(36864 * 2);
  short* cW2sw = (short*)carve(16384 * 2);
  int*   cnt   = (int*)carve((size_t)NN * 4);
  int*   offs  = (int*)carve((size_t)NN * 4);
  int*   bsum  = (int*)carve(256 * 4);
  int*   perm  = (int*)carve((size_t)NE * 4);

  float* xout_f = (float*)d_out;        // N*128
  float* pout_f = xout_f + NN * 128;    // N*3

  k_prep_weights<<<1008, 256, 0, stream>>>(We1, We2, Wn1, Wn2, cW1, cW2,
                                           W1sw, W2sw, Wn1sw, Wn2sw, cW1sw, cW2sw);
  k_init_xb<<<25000, 256, 0, stream>>>(x, Anode);
  k_edge_pre<<<3125, 256, 0, stream>>>(pos, eattr, ei, eaPad, nd);

  // build row-sorted edge permutation (CSR order)
  hipMemsetAsync(cnt, 0, (size_t)NN * 4, stream);
  k_hist<<<3125, 256, 0, stream>>>(ei, cnt);
  k_scan_block<<<196, 256, 0, stream>>>(cnt, offs, bsum);
  k_scan_top<<<1, 256, 0, stream>>>(bsum);
  k_scan_add<<<196, 256, 0, stream>>>(offs, bsum);
  k_scatter<<<3125, 256, 0, stream>>>(ei, offs, perm);

  for (int l = 0; l < 2; ++l) {
    hipMemsetAsync(agg, 0, (size_t)NN * 128 * 4, stream);
    k_edge_gemm<0><<<12500, 256, 0, stream>>>(Anode, eaPad, ei, perm,
        W1sw + l * 36864, W2sw + l * 16384, be1 + l * 128, be2 + l * 128,
        Watt + l * 128, batt + l, (const float*)nullptr, agg);
    k_nodeprep<<<25000, 256, 0, stream>>>(agg, Anode);
    k_node_gemm<<<391, 256, 0, stream>>>(Anode,
        Wn1sw + l * 32768, Wn2sw + l * 16384, bn1 + l * 128, bn2 + l * 128,
        l == 0 ? x : xcur, l == 0 ? xcur : xout_f);
  }
  hipMemsetAsync(pagg, 0, (size_t)NN * 3 * 4, stream);
  k_edge_gemm<1><<<12500, 256, 0, stream>>>(Anode, eaPad, ei, perm,
      cW1sw, cW2sw, cb1, cb2, cW3, (const float*)nullptr, nd, pagg);
  k_pos_final<<<587, 256, 0, stream>>>(pos, mask, pagg, pout_f);
}